// Round 1
// baseline (5082.398 us; speedup 1.0000x reference)
//
#include <hip/hip_runtime.h>
#include <hip/hip_bf16.h>
#include <math.h>

#define NODE_DIM 64
#define EDGE_DIM 32
#define HIDDEN   128
#define OUT_DIM  32
#define N_LAYERS 3
#define NGRAPH   128

// ---------------------------------------------------------------------------
// Sorting infrastructure: counting sort of edges by target node
// ---------------------------------------------------------------------------
__global__ void hist_kernel(const int* __restrict__ idx, int* __restrict__ cnt, int n) {
    int i = blockIdx.x * 256 + threadIdx.x;
    if (i < n) atomicAdd(&cnt[idx[i]], 1);
}

// exclusive scan of cnt[0..n) -> off[0..n]; single block of 1024 threads
__global__ void scan_kernel(const int* __restrict__ c, int* __restrict__ o, int n) {
    __shared__ int sh[1024];
    int t = threadIdx.x;
    int chunk = (n + 1023) >> 10;
    int lo = t * chunk, hi = lo + chunk;
    if (hi > n) hi = n;
    if (lo > n) lo = n;
    int s = 0;
    for (int i = lo; i < hi; ++i) s += c[i];
    sh[t] = s;
    __syncthreads();
    for (int d = 1; d < 1024; d <<= 1) {
        int v = (t >= d) ? sh[t - d] : 0;
        __syncthreads();
        sh[t] += v;
        __syncthreads();
    }
    int run = sh[t] - s;  // exclusive base
    for (int i = lo; i < hi; ++i) { o[i] = run; run += c[i]; }
    if (hi == n) o[n] = run;   // all such threads hold the total
}

__global__ void scatter_kernel(const int* __restrict__ src, const int* __restrict__ tgt,
                               const int* __restrict__ off, int* __restrict__ cur,
                               int* __restrict__ eidx, int* __restrict__ srcp, int n) {
    int e = blockIdx.x * 256 + threadIdx.x;
    if (e >= n) return;
    int t = tgt[e];
    int pos = off[t] + atomicAdd(&cur[t], 1);
    eidx[pos] = e;
    srcp[pos] = src[e];
}

// tiny serial scan for graph offsets (128 bins)
__global__ void small_scan_kernel(const int* __restrict__ c, int* __restrict__ o, int n) {
    if (threadIdx.x == 0 && blockIdx.x == 0) {
        int run = 0;
        for (int i = 0; i < n; ++i) { o[i] = run; run += c[i]; }
        o[n] = run;
    }
}

// ---------------------------------------------------------------------------
// Generic dense layer: Y[row, d] = (ACT?tanh:id)(X[row,:] @ W[:,d] + b[d]) (+Y if RESID)
// wave-per-row when M>=64: X reads are wave-uniform -> s_load
// ---------------------------------------------------------------------------
template <int K, int M, bool ACT, bool RESID>
__global__ __launch_bounds__(256) void dense_kernel(
    const float* __restrict__ X, const float* __restrict__ W,
    const float* __restrict__ bias, float* __restrict__ Y, int rows) {
    int tid = blockIdx.x * 256 + threadIdx.x;
    int row = tid / M;
    int d = tid - row * M;
    if (row >= rows) return;
    if (M >= 64) row = __builtin_amdgcn_readfirstlane(row);  // provably wave-uniform
    const float* __restrict__ x = X + (size_t)row * K;
    float acc = bias ? bias[d] : 0.f;
#pragma unroll
    for (int k = 0; k < K; ++k) acc += x[k] * W[k * M + d];
    if (ACT) acc = tanhf(acc);
    if (RESID) acc += Y[(size_t)row * M + d];
    Y[(size_t)row * M + d] = acc;
}

// ---------------------------------------------------------------------------
// Fused edge kernel (thread per permuted edge position p):
//   e = eidx[p]; ew = MLP2(edge_attr[e]); msg[p] = hd[srcp[p]] * ew;
//   score[p] = dot(msg[p], attn_v)
// Weight indices are loop-constant (wave-uniform) -> scalar loads.
// ---------------------------------------------------------------------------
__global__ __launch_bounds__(256) void edge_kernel(
    const float* __restrict__ edge_attr, const float* __restrict__ hd,
    const float* __restrict__ W1, const float* __restrict__ b1,
    const float* __restrict__ W2, const float* __restrict__ b2,
    const float* __restrict__ av,
    const int* __restrict__ eidx, const int* __restrict__ srcp,
    float* __restrict__ msg, float* __restrict__ score, int E) {
    int p = blockIdx.x * 256 + threadIdx.x;
    if (p >= E) return;
    int e = eidx[p];
    const float4* eav = (const float4*)(edge_attr + (size_t)e * EDGE_DIM);
    float a[EDGE_DIM];
#pragma unroll
    for (int q = 0; q < EDGE_DIM / 4; ++q) {
        float4 v = eav[q];
        a[4 * q] = v.x; a[4 * q + 1] = v.y; a[4 * q + 2] = v.z; a[4 * q + 3] = v.w;
    }
    float ew[NODE_DIM];
#pragma unroll
    for (int d = 0; d < NODE_DIM; ++d) ew[d] = b2[d];

#pragma unroll 1
    for (int j0 = 0; j0 < HIDDEN; j0 += 8) {
        float hj[8];
#pragma unroll
        for (int jj = 0; jj < 8; ++jj) hj[jj] = b1[j0 + jj];
#pragma unroll
        for (int k = 0; k < EDGE_DIM; ++k) {
            const float* wr = W1 + k * HIDDEN + j0;
            float4 w0 = *(const float4*)wr;
            float4 w1 = *(const float4*)(wr + 4);
            hj[0] += a[k] * w0.x; hj[1] += a[k] * w0.y;
            hj[2] += a[k] * w0.z; hj[3] += a[k] * w0.w;
            hj[4] += a[k] * w1.x; hj[5] += a[k] * w1.y;
            hj[6] += a[k] * w1.z; hj[7] += a[k] * w1.w;
        }
#pragma unroll
        for (int jj = 0; jj < 8; ++jj) {
            float t = tanhf(hj[jj]);
            const float* w2r = W2 + (j0 + jj) * NODE_DIM;
#pragma unroll
            for (int d0 = 0; d0 < NODE_DIM; d0 += 4) {
                float4 w = *(const float4*)(w2r + d0);
                ew[d0] += t * w.x; ew[d0 + 1] += t * w.y;
                ew[d0 + 2] += t * w.z; ew[d0 + 3] += t * w.w;
            }
        }
    }

    int s = srcp[p];
    const float4* hdv = (const float4*)(hd + (size_t)s * NODE_DIM);
    float4* mout = (float4*)(msg + (size_t)p * NODE_DIM);
    float sc = 0.f;
#pragma unroll
    for (int q = 0; q < NODE_DIM / 4; ++q) {
        float4 hv = hdv[q];
        float4 m;
        m.x = hv.x * ew[4 * q];     m.y = hv.y * ew[4 * q + 1];
        m.z = hv.z * ew[4 * q + 2]; m.w = hv.w * ew[4 * q + 3];
        sc += m.x * av[4 * q] + m.y * av[4 * q + 1] + m.z * av[4 * q + 2] + m.w * av[4 * q + 3];
        mout[q] = m;
    }
    score[p] = sc;
}

// ---------------------------------------------------------------------------
// Aggregation: wave per node; segment softmax over its edge range + weighted sum
// ---------------------------------------------------------------------------
__global__ __launch_bounds__(256) void agg_kernel(
    const float* __restrict__ msg, const float* __restrict__ score,
    const int* __restrict__ off, float* __restrict__ agg, int n) {
    int tid = blockIdx.x * 256 + threadIdx.x;
    int wid = tid >> 6;
    int lane = threadIdx.x & 63;
    if (wid >= n) return;
    wid = __builtin_amdgcn_readfirstlane(wid);
    int o0 = off[wid], o1 = off[wid + 1];
    float m = -INFINITY;
    for (int p = o0 + lane; p < o1; p += 64) m = fmaxf(m, score[p]);
#pragma unroll
    for (int s = 32; s; s >>= 1) m = fmaxf(m, __shfl_xor(m, s, 64));
    float dsum = 0.f;
    for (int p = o0 + lane; p < o1; p += 64) dsum += __expf(score[p] - m);
#pragma unroll
    for (int s = 32; s; s >>= 1) dsum += __shfl_xor(dsum, s, 64);
    float acc = 0.f;
    for (int p = o0; p < o1; ++p) {
        float w = __expf(score[p] - m);  // score[p] wave-uniform -> scalar load
        acc += w * msg[(size_t)p * NODE_DIM + lane];
    }
    agg[(size_t)wid * NODE_DIM + lane] = (o1 > o0) ? acc / dsum : 0.f;
}

// ---------------------------------------------------------------------------
// Mean pool per graph (batch sorted): block per graph, lane per dim
// ---------------------------------------------------------------------------
__global__ void pool_kernel(const float* __restrict__ h, const int* __restrict__ goff,
                            const int* __restrict__ gcnt, float* __restrict__ pooled) {
    int g = blockIdx.x;
    int d = threadIdx.x;
    int o0 = goff[g], o1 = goff[g + 1];
    float acc = 0.f;
    for (int n = o0; n < o1; ++n) acc += h[(size_t)n * NODE_DIM + d];
    int c = gcnt[g];
    if (c < 1) c = 1;
    pooled[g * NODE_DIM + d] = acc / (float)c;
}

// ---------------------------------------------------------------------------
extern "C" void kernel_launch(void* const* d_in, const int* in_sizes, int n_in,
                              void* d_out, int out_size, void* d_ws, size_t ws_size,
                              hipStream_t stream) {
    const float* x         = (const float*)d_in[0];
    const float* edge_attr = (const float*)d_in[1];
    const int*   ei        = (const int*)d_in[2];
    const int*   batch     = (const int*)d_in[3];
    const float* Wd        = (const float*)d_in[4];
    const float* fW1       = (const float*)d_in[5];
    const float* fb1       = (const float*)d_in[6];
    const float* fW2       = (const float*)d_in[7];
    const float* fb2       = (const float*)d_in[8];
    const float* av        = (const float*)d_in[9];
    const float* oW1       = (const float*)d_in[10];
    const float* ob1       = (const float*)d_in[11];
    const float* oW2       = (const float*)d_in[12];
    const float* ob2       = (const float*)d_in[13];
    const float* nW1       = (const float*)d_in[14];
    const float* nb1       = (const float*)d_in[15];
    const float* nW2       = (const float*)d_in[16];
    const float* nb2       = (const float*)d_in[17];
    float* out = (float*)d_out;

    const int N = in_sizes[0] / NODE_DIM;   // 50000
    const int E = in_sizes[2] / 2;          // 800000
    const int G = NGRAPH;

    // ---- workspace carve (256B-aligned) ----
    char* base = (char*)d_ws;
    size_t pos = 0;
    auto alloc = [&](size_t bytes) -> void* {
        pos = (pos + 255) & ~(size_t)255;
        void* r = base + pos;
        pos += bytes;
        return r;
    };
    int* cnt  = (int*)alloc((size_t)N * 4);
    int* cur  = (int*)alloc((size_t)N * 4);
    int* gcnt = (int*)alloc((size_t)G * 4);
    size_t zero_bytes = pos;  // zero everything up to here in one memset
    int* off  = (int*)alloc((size_t)(N + 1) * 4);
    int* goff = (int*)alloc((size_t)(G + 1) * 4);
    int* eidx = (int*)alloc((size_t)E * 4);
    int* srcp = (int*)alloc((size_t)E * 4);
    float* score  = (float*)alloc((size_t)E * 4);
    float* hd     = (float*)alloc((size_t)N * NODE_DIM * 4);
    float* h      = (float*)alloc((size_t)N * NODE_DIM * 4);
    float* agg    = (float*)alloc((size_t)N * NODE_DIM * 4);
    float* t1     = (float*)alloc((size_t)N * HIDDEN * 4);
    float* pooled = (float*)alloc((size_t)G * NODE_DIM * 4);
    float* t2     = (float*)alloc((size_t)G * HIDDEN * 4);
    float* msg    = (float*)alloc((size_t)E * NODE_DIM * 4);
    (void)ws_size;

    const int* src = ei;
    const int* tgt = ei + E;

    hipMemsetAsync(d_ws, 0, zero_bytes, stream);
    hist_kernel<<<(E + 255) / 256, 256, 0, stream>>>(tgt, cnt, E);
    scan_kernel<<<1, 1024, 0, stream>>>(cnt, off, N);
    scatter_kernel<<<(E + 255) / 256, 256, 0, stream>>>(src, tgt, off, cur, eidx, srcp, E);
    hist_kernel<<<(N + 255) / 256, 256, 0, stream>>>(batch, gcnt, N);
    small_scan_kernel<<<1, 64, 0, stream>>>(gcnt, goff, G);
    hipMemcpyAsync(h, x, (size_t)N * NODE_DIM * 4, hipMemcpyDeviceToDevice, stream);

    for (int i = 0; i < N_LAYERS; ++i) {
        dense_kernel<NODE_DIM, NODE_DIM, false, false>
            <<<(N * NODE_DIM + 255) / 256, 256, 0, stream>>>(
                h, Wd + (size_t)i * NODE_DIM * NODE_DIM, nullptr, hd, N);
        edge_kernel<<<(E + 255) / 256, 256, 0, stream>>>(
            edge_attr, hd,
            fW1 + (size_t)i * EDGE_DIM * HIDDEN, fb1 + (size_t)i * HIDDEN,
            fW2 + (size_t)i * HIDDEN * NODE_DIM, fb2 + (size_t)i * NODE_DIM,
            av + (size_t)i * NODE_DIM, eidx, srcp, msg, score, E);
        agg_kernel<<<(N + 3) / 4, 256, 0, stream>>>(msg, score, off, agg, N);
        dense_kernel<NODE_DIM, HIDDEN, true, false>
            <<<(N * HIDDEN + 255) / 256, 256, 0, stream>>>(
                agg, oW1 + (size_t)i * NODE_DIM * HIDDEN, ob1 + (size_t)i * HIDDEN, t1, N);
        dense_kernel<HIDDEN, NODE_DIM, false, true>
            <<<(N * NODE_DIM + 255) / 256, 256, 0, stream>>>(
                t1, oW2 + (size_t)i * HIDDEN * NODE_DIM, ob2 + (size_t)i * NODE_DIM, h, N);
    }

    pool_kernel<<<G, NODE_DIM, 0, stream>>>(h, goff, gcnt, pooled);
    dense_kernel<NODE_DIM, HIDDEN, true, false>
        <<<(G * HIDDEN + 255) / 256, 256, 0, stream>>>(pooled, nW1, nb1, t2, G);
    dense_kernel<HIDDEN, OUT_DIM, false, false>
        <<<(G * OUT_DIM + 255) / 256, 256, 0, stream>>>(t2, nW2, nb2, out, G);
}

// Round 2
// 1667.656 us; speedup vs baseline: 3.0476x; 3.0476x over previous
//
#include <hip/hip_runtime.h>
#include <hip/hip_bf16.h>
#include <math.h>

#define NODE_DIM 64
#define EDGE_DIM 32
#define HIDDEN   128
#define OUT_DIM  32
#define N_LAYERS 3
#define NGRAPH   128

typedef __attribute__((ext_vector_type(8))) short bf16x8;
typedef __attribute__((ext_vector_type(4))) float f32x4;

__device__ __forceinline__ unsigned short f2bf(float f) {
    unsigned u = __float_as_uint(f);
    u = (u + 0x7fffu + ((u >> 16) & 1u)) >> 16;
    return (unsigned short)u;
}
__device__ __forceinline__ float bf2f(unsigned short h) {
    return __uint_as_float((unsigned)h << 16);
}

// ---------------------------------------------------------------------------
// Sorting infrastructure: counting sort of edges by target node
// ---------------------------------------------------------------------------
__global__ void hist_kernel(const int* __restrict__ idx, int* __restrict__ cnt, int n) {
    int i = blockIdx.x * 256 + threadIdx.x;
    if (i < n) atomicAdd(&cnt[idx[i]], 1);
}

__global__ void scan_kernel(const int* __restrict__ c, int* __restrict__ o, int n) {
    __shared__ int sh[1024];
    int t = threadIdx.x;
    int chunk = (n + 1023) >> 10;
    int lo = t * chunk, hi = lo + chunk;
    if (hi > n) hi = n;
    if (lo > n) lo = n;
    int s = 0;
    for (int i = lo; i < hi; ++i) s += c[i];
    sh[t] = s;
    __syncthreads();
    for (int d = 1; d < 1024; d <<= 1) {
        int v = (t >= d) ? sh[t - d] : 0;
        __syncthreads();
        sh[t] += v;
        __syncthreads();
    }
    int run = sh[t] - s;
    for (int i = lo; i < hi; ++i) { o[i] = run; run += c[i]; }
    if (hi == n) o[n] = run;
}

__global__ void scatter_kernel(const int* __restrict__ src, const int* __restrict__ tgt,
                               const int* __restrict__ off, int* __restrict__ cur,
                               int* __restrict__ eidx, int* __restrict__ srcp, int n) {
    int e = blockIdx.x * 256 + threadIdx.x;
    if (e >= n) return;
    int t = tgt[e];
    int pos = off[t] + atomicAdd(&cur[t], 1);
    eidx[pos] = e;
    srcp[pos] = src[e];
}

__global__ void small_scan_kernel(const int* __restrict__ c, int* __restrict__ o, int n) {
    if (threadIdx.x == 0 && blockIdx.x == 0) {
        int run = 0;
        for (int i = 0; i < n; ++i) { o[i] = run; run += c[i]; }
        o[n] = run;
    }
}

// ---------------------------------------------------------------------------
// Prep: permute+convert edge_attr to bf16 in target-sorted order
// ---------------------------------------------------------------------------
__global__ __launch_bounds__(256) void perm_ea_kernel(
    const float* __restrict__ ea, const int* __restrict__ eidx,
    unsigned short* __restrict__ out, int E) {
    int p = blockIdx.x * 256 + threadIdx.x;
    if (p >= E) return;
    int e = eidx[p];
    const float4* r = (const float4*)(ea + (size_t)e * EDGE_DIM);
    union { unsigned short us[EDGE_DIM]; uint4 u4[EDGE_DIM / 8]; } tmp;
#pragma unroll
    for (int q = 0; q < EDGE_DIM / 4; ++q) {
        float4 v = r[q];
        tmp.us[4 * q]     = f2bf(v.x);
        tmp.us[4 * q + 1] = f2bf(v.y);
        tmp.us[4 * q + 2] = f2bf(v.z);
        tmp.us[4 * q + 3] = f2bf(v.w);
    }
    uint4* o = (uint4*)(out + (size_t)p * EDGE_DIM);
#pragma unroll
    for (int k = 0; k < EDGE_DIM / 8; ++k) o[k] = tmp.u4[k];
}

// ---------------------------------------------------------------------------
// Prep: swizzle W1^T, W2^T into MFMA A-operand fragment order (bf16), 3 layers
// A-frag (16x16x32): A[m = lane&15][k = (lane>>4)*8 + j], j=0..7
// W1sw[i][t][lane][j] = W1[i][ (q*8+j) ][ 16t + e ]      (t: 8 hid tiles)
// W2sw[i][nt*4+s][lane][j] = W2[i][ 32s+8q+j ][ 16nt+e ] (nt: 4 dim tiles, s: 4 ksteps)
// ---------------------------------------------------------------------------
__global__ void swizzle_w_kernel(const float* __restrict__ fW1, const float* __restrict__ fW2,
                                 unsigned short* __restrict__ W1sw,
                                 unsigned short* __restrict__ W2sw) {
    int L = threadIdx.x;  // 64 threads
    int e = L & 15, q = L >> 4;
    for (int i = 0; i < N_LAYERS; ++i) {
        const float* W1 = fW1 + (size_t)i * EDGE_DIM * HIDDEN;
        unsigned short* o1 = W1sw + (size_t)i * 8 * 64 * 8;
        for (int t = 0; t < 8; ++t)
            for (int j = 0; j < 8; ++j)
                o1[(t * 64 + L) * 8 + j] = f2bf(W1[(q * 8 + j) * HIDDEN + 16 * t + e]);
        const float* W2 = fW2 + (size_t)i * HIDDEN * NODE_DIM;
        unsigned short* o2 = W2sw + (size_t)i * 16 * 64 * 8;
        for (int nt = 0; nt < 4; ++nt)
            for (int s = 0; s < 4; ++s)
                for (int j = 0; j < 8; ++j)
                    o2[((nt * 4 + s) * 64 + L) * 8 + j] =
                        f2bf(W2[(32 * s + 8 * q + j) * NODE_DIM + 16 * nt + e]);
    }
}

// ---------------------------------------------------------------------------
// Fused MFMA edge kernel: wave per 16 edges.
// GEMM1 (transposed): C1^T[hid][edge] = W1^T · ea^T  -> per-lane: one edge,
//   hid = 16t + 4q + j  -> tanh+bias -> bf16 -> LDS (per-wave slab, no barrier)
// GEMM2 (transposed): ew^T[dim][edge] = W2^T · H^T
// Epilogue: ew bf16 out, score = dot(hd[src]*ew, av) via shfl reduce.
// ---------------------------------------------------------------------------
#define HSTRIDE 136  // 128 + 8 pad (keeps 16B alignment for ds_read_b128)

__global__ __launch_bounds__(256) void edge_mfma_kernel(
    const unsigned short* __restrict__ ea_p, const float* __restrict__ hd,
    const unsigned short* __restrict__ W1sw, const float* __restrict__ b1,
    const unsigned short* __restrict__ W2sw, const float* __restrict__ b2,
    const float* __restrict__ av, const int* __restrict__ srcp,
    unsigned short* __restrict__ ew, float* __restrict__ score, int E) {
    __shared__ unsigned short Hl[4][16 * HSTRIDE];
    int wave = threadIdx.x >> 6, lane = threadIdx.x & 63;
    int e = lane & 15, q = lane >> 4;
    int p0 = blockIdx.x * 64 + wave * 16;
    if (p0 >= E) return;

    // B-frag: ea^T[k=8q+j][edge=e] = ea_p[p0+e][8q+j] -- one 16B load
    bf16x8 eaf = *(const bf16x8*)(ea_p + (size_t)(p0 + e) * EDGE_DIM + q * 8);

    f32x4 c1[8];
#pragma unroll
    for (int t = 0; t < 8; ++t) {
        bf16x8 a = *(const bf16x8*)(W1sw + (t * 64 + lane) * 8);
        c1[t] = __builtin_amdgcn_mfma_f32_16x16x32_bf16(a, eaf, (f32x4){0.f, 0.f, 0.f, 0.f}, 0, 0, 0);
    }

    unsigned short* hrow = &Hl[wave][e * HSTRIDE];
#pragma unroll
    for (int t = 0; t < 8; ++t) {
        float4 b = *(const float4*)(b1 + 16 * t + 4 * q);
        unsigned h0 = f2bf(tanhf(c1[t][0] + b.x));
        unsigned h1 = f2bf(tanhf(c1[t][1] + b.y));
        unsigned h2 = f2bf(tanhf(c1[t][2] + b.z));
        unsigned h3 = f2bf(tanhf(c1[t][3] + b.w));
        uint2 pk;
        pk.x = h0 | (h1 << 16);
        pk.y = h2 | (h3 << 16);
        *(uint2*)(hrow + 16 * t + 4 * q) = pk;  // ds_write_b64
    }

    // GEMM2: B-frag from LDS: H[edge=e][k = 32s + 8q + j] -- ds_read_b128
    f32x4 c2[4] = {{0.f, 0.f, 0.f, 0.f}, {0.f, 0.f, 0.f, 0.f},
                   {0.f, 0.f, 0.f, 0.f}, {0.f, 0.f, 0.f, 0.f}};
#pragma unroll
    for (int s = 0; s < 4; ++s) {
        bf16x8 hf = *(const bf16x8*)(hrow + 32 * s + 8 * q);
#pragma unroll
        for (int nt = 0; nt < 4; ++nt) {
            bf16x8 a = *(const bf16x8*)(W2sw + ((nt * 4 + s) * 64 + lane) * 8);
            c2[nt] = __builtin_amdgcn_mfma_f32_16x16x32_bf16(a, hf, c2[nt], 0, 0, 0);
        }
    }

    // Epilogue: lane owns edge p0+e, dims {16nt + 4q + j}
    int sidx = srcp[p0 + e];
    float sc = 0.f;
#pragma unroll
    for (int nt = 0; nt < 4; ++nt) {
        float4 bb = *(const float4*)(b2 + 16 * nt + 4 * q);
        float4 vv = *(const float4*)(av + 16 * nt + 4 * q);
        float4 hh = *(const float4*)(hd + (size_t)sidx * NODE_DIM + 16 * nt + 4 * q);
        float e0 = c2[nt][0] + bb.x, e1 = c2[nt][1] + bb.y;
        float e2 = c2[nt][2] + bb.z, e3 = c2[nt][3] + bb.w;
        uint2 pk;
        pk.x = (unsigned)f2bf(e0) | ((unsigned)f2bf(e1) << 16);
        pk.y = (unsigned)f2bf(e2) | ((unsigned)f2bf(e3) << 16);
        *(uint2*)(ew + (size_t)(p0 + e) * NODE_DIM + 16 * nt + 4 * q) = pk;
        sc += hh.x * e0 * vv.x + hh.y * e1 * vv.y + hh.z * e2 * vv.z + hh.w * e3 * vv.w;
    }
    sc += __shfl_xor(sc, 16, 64);
    sc += __shfl_xor(sc, 32, 64);
    if (q == 0) score[p0 + e] = sc;
}

// ---------------------------------------------------------------------------
// Generic dense layer (fp32, node-side): Y = act(X@W + b) (+Y if RESID)
// ---------------------------------------------------------------------------
template <int K, int M, bool ACT, bool RESID>
__global__ __launch_bounds__(256) void dense_kernel(
    const float* __restrict__ X, const float* __restrict__ W,
    const float* __restrict__ bias, float* __restrict__ Y, int rows) {
    int tid = blockIdx.x * 256 + threadIdx.x;
    int row = tid / M;
    int d = tid - row * M;
    if (row >= rows) return;
    if (M >= 64) row = __builtin_amdgcn_readfirstlane(row);
    const float* __restrict__ x = X + (size_t)row * K;
    float acc = bias ? bias[d] : 0.f;
#pragma unroll
    for (int k = 0; k < K; ++k) acc += x[k] * W[k * M + d];
    if (ACT) acc = tanhf(acc);
    if (RESID) acc += Y[(size_t)row * M + d];
    Y[(size_t)row * M + d] = acc;
}

// ---------------------------------------------------------------------------
// Aggregation: wave per node; softmax over scores, msg recomputed on the fly
// ---------------------------------------------------------------------------
__global__ __launch_bounds__(256) void agg_kernel(
    const unsigned short* __restrict__ ew, const float* __restrict__ score,
    const float* __restrict__ hd, const int* __restrict__ srcp,
    const int* __restrict__ off, float* __restrict__ agg, int n) {
    int tid = blockIdx.x * 256 + threadIdx.x;
    int wid = tid >> 6;
    int lane = threadIdx.x & 63;
    if (wid >= n) return;
    wid = __builtin_amdgcn_readfirstlane(wid);
    int o0 = off[wid], o1 = off[wid + 1];
    float m = -INFINITY;
    for (int p = o0 + lane; p < o1; p += 64) m = fmaxf(m, score[p]);
#pragma unroll
    for (int s = 32; s; s >>= 1) m = fmaxf(m, __shfl_xor(m, s, 64));
    float dsum = 0.f;
    for (int p = o0 + lane; p < o1; p += 64) dsum += __expf(score[p] - m);
#pragma unroll
    for (int s = 32; s; s >>= 1) dsum += __shfl_xor(dsum, s, 64);
    float acc = 0.f;
    for (int p = o0; p < o1; ++p) {
        float w = __expf(score[p] - m);           // lane-uniform
        int s = srcp[p];                          // lane-uniform
        float ewv = bf2f(ew[(size_t)p * NODE_DIM + lane]);
        acc += w * hd[(size_t)s * NODE_DIM + lane] * ewv;
    }
    agg[(size_t)wid * NODE_DIM + lane] = (o1 > o0) ? acc / dsum : 0.f;
}

// ---------------------------------------------------------------------------
// Mean pool per graph
// ---------------------------------------------------------------------------
__global__ void pool_kernel(const float* __restrict__ h, const int* __restrict__ goff,
                            const int* __restrict__ gcnt, float* __restrict__ pooled) {
    int g = blockIdx.x;
    int d = threadIdx.x;
    int o0 = goff[g], o1 = goff[g + 1];
    float acc = 0.f;
    for (int n = o0; n < o1; ++n) acc += h[(size_t)n * NODE_DIM + d];
    int c = gcnt[g];
    if (c < 1) c = 1;
    pooled[g * NODE_DIM + d] = acc / (float)c;
}

// ---------------------------------------------------------------------------
extern "C" void kernel_launch(void* const* d_in, const int* in_sizes, int n_in,
                              void* d_out, int out_size, void* d_ws, size_t ws_size,
                              hipStream_t stream) {
    const float* x         = (const float*)d_in[0];
    const float* edge_attr = (const float*)d_in[1];
    const int*   ei        = (const int*)d_in[2];
    const int*   batch     = (const int*)d_in[3];
    const float* Wd        = (const float*)d_in[4];
    const float* fW1       = (const float*)d_in[5];
    const float* fb1       = (const float*)d_in[6];
    const float* fW2       = (const float*)d_in[7];
    const float* fb2       = (const float*)d_in[8];
    const float* av        = (const float*)d_in[9];
    const float* oW1       = (const float*)d_in[10];
    const float* ob1       = (const float*)d_in[11];
    const float* oW2       = (const float*)d_in[12];
    const float* ob2       = (const float*)d_in[13];
    const float* nW1       = (const float*)d_in[14];
    const float* nb1       = (const float*)d_in[15];
    const float* nW2       = (const float*)d_in[16];
    const float* nb2       = (const float*)d_in[17];
    float* out = (float*)d_out;

    const int N = in_sizes[0] / NODE_DIM;   // 50000
    const int E = in_sizes[2] / 2;          // 800000
    const int G = NGRAPH;

    char* base = (char*)d_ws;
    size_t pos = 0;
    auto alloc = [&](size_t bytes) -> void* {
        pos = (pos + 255) & ~(size_t)255;
        void* r = base + pos;
        pos += bytes;
        return r;
    };
    int* cnt  = (int*)alloc((size_t)N * 4);
    int* cur  = (int*)alloc((size_t)N * 4);
    int* gcnt = (int*)alloc((size_t)G * 4);
    size_t zero_bytes = pos;
    int* off  = (int*)alloc((size_t)(N + 1) * 4);
    int* goff = (int*)alloc((size_t)(G + 1) * 4);
    int* eidx = (int*)alloc((size_t)E * 4);
    int* srcp = (int*)alloc((size_t)E * 4);
    float* score = (float*)alloc((size_t)E * 4);
    float* hd    = (float*)alloc((size_t)N * NODE_DIM * 4);
    float* h     = (float*)alloc((size_t)N * NODE_DIM * 4);
    float* agg   = (float*)alloc((size_t)N * NODE_DIM * 4);
    float* t1    = (float*)alloc((size_t)N * HIDDEN * 4);
    float* pooled = (float*)alloc((size_t)G * NODE_DIM * 4);
    float* t2     = (float*)alloc((size_t)G * HIDDEN * 4);
    unsigned short* ea_p = (unsigned short*)alloc((size_t)E * EDGE_DIM * 2);
    unsigned short* ew   = (unsigned short*)alloc((size_t)E * NODE_DIM * 2);
    unsigned short* W1sw = (unsigned short*)alloc((size_t)N_LAYERS * 8 * 64 * 8 * 2);
    unsigned short* W2sw = (unsigned short*)alloc((size_t)N_LAYERS * 16 * 64 * 8 * 2);
    (void)ws_size;

    const int* src = ei;
    const int* tgt = ei + E;

    hipMemsetAsync(d_ws, 0, zero_bytes, stream);
    hist_kernel<<<(E + 255) / 256, 256, 0, stream>>>(tgt, cnt, E);
    scan_kernel<<<1, 1024, 0, stream>>>(cnt, off, N);
    scatter_kernel<<<(E + 255) / 256, 256, 0, stream>>>(src, tgt, off, cur, eidx, srcp, E);
    hist_kernel<<<(N + 255) / 256, 256, 0, stream>>>(batch, gcnt, N);
    small_scan_kernel<<<1, 64, 0, stream>>>(gcnt, goff, G);
    perm_ea_kernel<<<(E + 255) / 256, 256, 0, stream>>>(edge_attr, eidx, ea_p, E);
    swizzle_w_kernel<<<1, 64, 0, stream>>>(fW1, fW2, W1sw, W2sw);
    hipMemcpyAsync(h, x, (size_t)N * NODE_DIM * 4, hipMemcpyDeviceToDevice, stream);

    for (int i = 0; i < N_LAYERS; ++i) {
        dense_kernel<NODE_DIM, NODE_DIM, false, false>
            <<<(N * NODE_DIM + 255) / 256, 256, 0, stream>>>(
                h, Wd + (size_t)i * NODE_DIM * NODE_DIM, nullptr, hd, N);
        edge_mfma_kernel<<<(E + 63) / 64, 256, 0, stream>>>(
            ea_p, hd,
            W1sw + (size_t)i * 8 * 64 * 8, fb1 + (size_t)i * HIDDEN,
            W2sw + (size_t)i * 16 * 64 * 8, fb2 + (size_t)i * NODE_DIM,
            av + (size_t)i * NODE_DIM, srcp, ew, score, E);
        agg_kernel<<<(N + 3) / 4, 256, 0, stream>>>(ew, score, hd, srcp, off, agg, N);
        dense_kernel<NODE_DIM, HIDDEN, true, false>
            <<<(N * HIDDEN + 255) / 256, 256, 0, stream>>>(
                agg, oW1 + (size_t)i * NODE_DIM * HIDDEN, ob1 + (size_t)i * HIDDEN, t1, N);
        dense_kernel<HIDDEN, NODE_DIM, false, true>
            <<<(N * NODE_DIM + 255) / 256, 256, 0, stream>>>(
                t1, oW2 + (size_t)i * HIDDEN * NODE_DIM, ob2 + (size_t)i * NODE_DIM, h, N);
    }

    pool_kernel<<<G, NODE_DIM, 0, stream>>>(h, goff, gcnt, pooled);
    dense_kernel<NODE_DIM, HIDDEN, true, false>
        <<<(G * HIDDEN + 255) / 256, 256, 0, stream>>>(pooled, nW1, nb1, t2, G);
    dense_kernel<HIDDEN, OUT_DIM, false, false>
        <<<(G * OUT_DIM + 255) / 256, 256, 0, stream>>>(t2, nW2, nb2, out, G);
}

// Round 3
// 1418.798 us; speedup vs baseline: 3.5822x; 1.1754x over previous
//
#include <hip/hip_runtime.h>
#include <hip/hip_bf16.h>
#include <math.h>

#define NODE_DIM 64
#define EDGE_DIM 32
#define HIDDEN   128
#define OUT_DIM  32
#define N_LAYERS 3
#define NGRAPH   128

typedef __attribute__((ext_vector_type(8))) short bf16x8;
typedef __attribute__((ext_vector_type(4))) float f32x4;

__device__ __forceinline__ unsigned short f2bf(float f) {
    unsigned u = __float_as_uint(f);
    u = (u + 0x7fffu + ((u >> 16) & 1u)) >> 16;
    return (unsigned short)u;
}
__device__ __forceinline__ float bf2f(unsigned short h) {
    return __uint_as_float((unsigned)h << 16);
}
// tanh(x) = sign(x) * (1 - e) / (1 + e), e = exp(-2|x|)  (~7 VALU vs ~40 libm)
__device__ __forceinline__ float fast_tanh(float x) {
    float ax = fabsf(x);
    float e = __expf(-2.f * ax);
    float r = __builtin_amdgcn_rcpf(1.f + e);
    float t = (1.f - e) * r;
    return __builtin_copysignf(t, x);
}

// ---------------------------------------------------------------------------
// Counting sort of edges by target node
// ---------------------------------------------------------------------------
__global__ void hist_kernel(const int* __restrict__ idx, int* __restrict__ cnt, int n) {
    int i = blockIdx.x * 256 + threadIdx.x;
    if (i < n) atomicAdd(&cnt[idx[i]], 1);
}

__global__ void scan_kernel(const int* __restrict__ c, int* __restrict__ o, int n) {
    __shared__ int sh[1024];
    int t = threadIdx.x;
    int chunk = (n + 1023) >> 10;
    int lo = t * chunk, hi = lo + chunk;
    if (hi > n) hi = n;
    if (lo > n) lo = n;
    int s = 0;
    for (int i = lo; i < hi; ++i) s += c[i];
    sh[t] = s;
    __syncthreads();
    for (int d = 1; d < 1024; d <<= 1) {
        int v = (t >= d) ? sh[t - d] : 0;
        __syncthreads();
        sh[t] += v;
        __syncthreads();
    }
    int run = sh[t] - s;
    for (int i = lo; i < hi; ++i) { o[i] = run; run += c[i]; }
    if (hi == n) o[n] = run;
}

__global__ void scatter_kernel(const int* __restrict__ src, const int* __restrict__ tgt,
                               const int* __restrict__ off, int* __restrict__ cur,
                               int* __restrict__ eidx, int* __restrict__ srcp, int n) {
    int e = blockIdx.x * 256 + threadIdx.x;
    if (e >= n) return;
    int t = tgt[e];
    int pos = off[t] + atomicAdd(&cur[t], 1);
    eidx[pos] = e;
    srcp[pos] = src[e];
}

// 128-entry exclusive scan, one block of 128 threads
__global__ void gscan_kernel(const int* __restrict__ c, int* __restrict__ o, int n) {
    __shared__ int sh[128];
    int t = threadIdx.x;
    int v = (t < n) ? c[t] : 0;
    sh[t] = v;
    __syncthreads();
    for (int d = 1; d < 128; d <<= 1) {
        int u = (t >= d) ? sh[t - d] : 0;
        __syncthreads();
        sh[t] += u;
        __syncthreads();
    }
    if (t < n) o[t] = sh[t] - v;
    if (t == n - 1) o[n] = sh[t];
}

// ---------------------------------------------------------------------------
// Swizzle W1^T, W2^T into MFMA A-operand fragment order (bf16); block per layer
// ---------------------------------------------------------------------------
__global__ void swizzle_w_kernel(const float* __restrict__ fW1, const float* __restrict__ fW2,
                                 unsigned short* __restrict__ W1sw,
                                 unsigned short* __restrict__ W2sw) {
    int i = blockIdx.x;  // layer
    int L = threadIdx.x; // 64 threads
    int e = L & 15, q = L >> 4;
    const float* W1 = fW1 + (size_t)i * EDGE_DIM * HIDDEN;
    unsigned short* o1 = W1sw + (size_t)i * 8 * 64 * 8;
    for (int t = 0; t < 8; ++t)
        for (int j = 0; j < 8; ++j)
            o1[(t * 64 + L) * 8 + j] = f2bf(W1[(q * 8 + j) * HIDDEN + 16 * t + e]);
    const float* W2 = fW2 + (size_t)i * HIDDEN * NODE_DIM;
    unsigned short* o2 = W2sw + (size_t)i * 16 * 64 * 8;
    for (int nt = 0; nt < 4; ++nt)
        for (int s = 0; s < 4; ++s)
            for (int j = 0; j < 8; ++j)
                o2[((nt * 4 + s) * 64 + L) * 8 + j] =
                    f2bf(W2[(32 * s + 8 * q + j) * NODE_DIM + 16 * nt + e]);
}

// ---------------------------------------------------------------------------
// Fused MFMA edge kernel: wave per 16 sorted edges; gathers fp32 edge_attr
// via eidx, converts to bf16 in-register. GEMM1^T -> tanh -> LDS -> GEMM2^T.
// ---------------------------------------------------------------------------
#define HSTRIDE 136  // 128 + 8 pad, keeps 16B alignment for ds_read_b128

__global__ __launch_bounds__(256) void edge_mfma_kernel(
    const float* __restrict__ ea, const int* __restrict__ eidx,
    const float* __restrict__ hd,
    const unsigned short* __restrict__ W1sw, const float* __restrict__ b1,
    const unsigned short* __restrict__ W2sw, const float* __restrict__ b2,
    const float* __restrict__ av, const int* __restrict__ srcp,
    unsigned short* __restrict__ ew, float* __restrict__ score, int E) {
    __shared__ unsigned short Hl[4][16 * HSTRIDE];
    int wave = threadIdx.x >> 6, lane = threadIdx.x & 63;
    int e = lane & 15, q = lane >> 4;
    int p0 = blockIdx.x * 64 + wave * 16;
    if (p0 >= E) return;

    // B-frag: ea[edge=e][k=8q+j], gathered fp32 -> bf16
    int esrc = eidx[p0 + e];
    const float4* ear = (const float4*)(ea + (size_t)esrc * EDGE_DIM + q * 8);
    float4 a0 = ear[0], a1 = ear[1];
    union { bf16x8 v; unsigned short us[8]; } eau;
    eau.us[0] = f2bf(a0.x); eau.us[1] = f2bf(a0.y);
    eau.us[2] = f2bf(a0.z); eau.us[3] = f2bf(a0.w);
    eau.us[4] = f2bf(a1.x); eau.us[5] = f2bf(a1.y);
    eau.us[6] = f2bf(a1.z); eau.us[7] = f2bf(a1.w);
    bf16x8 eaf = eau.v;

    f32x4 c1[8];
#pragma unroll
    for (int t = 0; t < 8; ++t) {
        bf16x8 a = *(const bf16x8*)(W1sw + (t * 64 + lane) * 8);
        c1[t] = __builtin_amdgcn_mfma_f32_16x16x32_bf16(a, eaf, (f32x4){0.f, 0.f, 0.f, 0.f}, 0, 0, 0);
    }

    unsigned short* hrow = &Hl[wave][e * HSTRIDE];
#pragma unroll
    for (int t = 0; t < 8; ++t) {
        float4 b = *(const float4*)(b1 + 16 * t + 4 * q);
        unsigned h0 = f2bf(fast_tanh(c1[t][0] + b.x));
        unsigned h1 = f2bf(fast_tanh(c1[t][1] + b.y));
        unsigned h2 = f2bf(fast_tanh(c1[t][2] + b.z));
        unsigned h3 = f2bf(fast_tanh(c1[t][3] + b.w));
        uint2 pk;
        pk.x = h0 | (h1 << 16);
        pk.y = h2 | (h3 << 16);
        *(uint2*)(hrow + 16 * t + 4 * q) = pk;  // ds_write_b64
    }

    f32x4 c2[4] = {{0.f, 0.f, 0.f, 0.f}, {0.f, 0.f, 0.f, 0.f},
                   {0.f, 0.f, 0.f, 0.f}, {0.f, 0.f, 0.f, 0.f}};
#pragma unroll
    for (int s = 0; s < 4; ++s) {
        bf16x8 hf = *(const bf16x8*)(hrow + 32 * s + 8 * q);
#pragma unroll
        for (int nt = 0; nt < 4; ++nt) {
            bf16x8 a = *(const bf16x8*)(W2sw + ((nt * 4 + s) * 64 + lane) * 8);
            c2[nt] = __builtin_amdgcn_mfma_f32_16x16x32_bf16(a, hf, c2[nt], 0, 0, 0);
        }
    }

    int sidx = srcp[p0 + e];
    float sc = 0.f;
#pragma unroll
    for (int nt = 0; nt < 4; ++nt) {
        float4 bb = *(const float4*)(b2 + 16 * nt + 4 * q);
        float4 vv = *(const float4*)(av + 16 * nt + 4 * q);
        float4 hh = *(const float4*)(hd + (size_t)sidx * NODE_DIM + 16 * nt + 4 * q);
        float e0 = c2[nt][0] + bb.x, e1 = c2[nt][1] + bb.y;
        float e2 = c2[nt][2] + bb.z, e3 = c2[nt][3] + bb.w;
        uint2 pk;
        pk.x = (unsigned)f2bf(e0) | ((unsigned)f2bf(e1) << 16);
        pk.y = (unsigned)f2bf(e2) | ((unsigned)f2bf(e3) << 16);
        *(uint2*)(ew + (size_t)(p0 + e) * NODE_DIM + 16 * nt + 4 * q) = pk;
        sc += hh.x * e0 * vv.x + hh.y * e1 * vv.y + hh.z * e2 * vv.z + hh.w * e3 * vv.w;
    }
    sc += __shfl_xor(sc, 16, 64);
    sc += __shfl_xor(sc, 32, 64);
    if (q == 0) score[p0 + e] = sc;
}

// ---------------------------------------------------------------------------
// Generic dense layer (fp32, node-side)
// ---------------------------------------------------------------------------
template <int K, int M, bool ACT, bool RESID>
__global__ __launch_bounds__(256) void dense_kernel(
    const float* __restrict__ X, const float* __restrict__ W,
    const float* __restrict__ bias, float* __restrict__ Y, int rows) {
    int tid = blockIdx.x * 256 + threadIdx.x;
    int row = tid / M;
    int d = tid - row * M;
    if (row >= rows) return;
    if (M >= 64) row = __builtin_amdgcn_readfirstlane(row);
    const float* __restrict__ x = X + (size_t)row * K;
    float acc = bias ? bias[d] : 0.f;
#pragma unroll
    for (int k = 0; k < K; ++k) acc += x[k] * W[k * M + d];
    if (ACT) acc = fast_tanh(acc);
    if (RESID) acc += Y[(size_t)row * M + d];
    Y[(size_t)row * M + d] = acc;
}

// ---------------------------------------------------------------------------
// Aggregation: wave per node; 8 edges x 8 dim-groups per iteration
// ---------------------------------------------------------------------------
__global__ __launch_bounds__(256) void agg_kernel(
    const unsigned short* __restrict__ ew, const float* __restrict__ score,
    const float* __restrict__ hd, const int* __restrict__ srcp,
    const int* __restrict__ off, float* __restrict__ agg, int n) {
    int tid = blockIdx.x * 256 + threadIdx.x;
    int wid = tid >> 6;
    int lane = threadIdx.x & 63;
    if (wid >= n) return;
    wid = __builtin_amdgcn_readfirstlane(wid);
    int o0 = off[wid], o1 = off[wid + 1];
    int g = lane >> 3, s = lane & 7;
    if (o1 <= o0) {
        if (g == 0) {
            float4 z = {0.f, 0.f, 0.f, 0.f};
            float4* dst = (float4*)(agg + (size_t)wid * NODE_DIM + s * 8);
            dst[0] = z; dst[1] = z;
        }
        return;
    }
    float m = -INFINITY;
    for (int p = o0 + lane; p < o1; p += 64) m = fmaxf(m, score[p]);
#pragma unroll
    for (int t = 32; t; t >>= 1) m = fmaxf(m, __shfl_xor(m, t, 64));
    float dsum = 0.f;
    for (int p = o0 + lane; p < o1; p += 64) dsum += __expf(score[p] - m);
#pragma unroll
    for (int t = 32; t; t >>= 1) dsum += __shfl_xor(dsum, t, 64);

    float acc[8] = {0.f, 0.f, 0.f, 0.f, 0.f, 0.f, 0.f, 0.f};
    for (int p = o0; p < o1; p += 8) {
        int pe = p + g;
        int pc = (pe < o1) ? pe : (o1 - 1);
        float w = (pe < o1) ? __expf(score[pc] - m) : 0.f;
        int sidx = srcp[pc];
        union { bf16x8 v; unsigned short us[8]; } eu;
        eu.v = *(const bf16x8*)(ew + (size_t)pc * NODE_DIM + s * 8);
        const float4* hr = (const float4*)(hd + (size_t)sidx * NODE_DIM + s * 8);
        float4 h0 = hr[0], h1 = hr[1];
        acc[0] += w * h0.x * bf2f(eu.us[0]);
        acc[1] += w * h0.y * bf2f(eu.us[1]);
        acc[2] += w * h0.z * bf2f(eu.us[2]);
        acc[3] += w * h0.w * bf2f(eu.us[3]);
        acc[4] += w * h1.x * bf2f(eu.us[4]);
        acc[5] += w * h1.y * bf2f(eu.us[5]);
        acc[6] += w * h1.z * bf2f(eu.us[6]);
        acc[7] += w * h1.w * bf2f(eu.us[7]);
    }
#pragma unroll
    for (int j = 0; j < 8; ++j) {
        acc[j] += __shfl_xor(acc[j], 8, 64);
        acc[j] += __shfl_xor(acc[j], 16, 64);
        acc[j] += __shfl_xor(acc[j], 32, 64);
    }
    if (g == 0) {
        float inv = __builtin_amdgcn_rcpf(dsum);
        // one Newton step for accuracy: inv = inv*(2 - dsum*inv)
        inv = inv * (2.f - dsum * inv);
        float4 r0 = {acc[0] * inv, acc[1] * inv, acc[2] * inv, acc[3] * inv};
        float4 r1 = {acc[4] * inv, acc[5] * inv, acc[6] * inv, acc[7] * inv};
        float4* dst = (float4*)(agg + (size_t)wid * NODE_DIM + s * 8);
        dst[0] = r0; dst[1] = r1;
    }
}

// ---------------------------------------------------------------------------
// Mean pool per graph: 4 waves per graph + LDS reduce
// ---------------------------------------------------------------------------
__global__ __launch_bounds__(256) void pool_kernel(const float* __restrict__ h,
                                                   const int* __restrict__ goff,
                                                   float* __restrict__ pooled) {
    __shared__ float sh[4][NODE_DIM];
    int g = blockIdx.x;
    int w = threadIdx.x >> 6, d = threadIdx.x & 63;
    int o0 = goff[g], o1 = goff[g + 1];
    float acc = 0.f;
    for (int n = o0 + w; n < o1; n += 4) acc += h[(size_t)n * NODE_DIM + d];
    sh[w][d] = acc;
    __syncthreads();
    if (w == 0) {
        float sum = sh[0][d] + sh[1][d] + sh[2][d] + sh[3][d];
        int c = o1 - o0;
        if (c < 1) c = 1;
        pooled[g * NODE_DIM + d] = sum / (float)c;
    }
}

// ---------------------------------------------------------------------------
extern "C" void kernel_launch(void* const* d_in, const int* in_sizes, int n_in,
                              void* d_out, int out_size, void* d_ws, size_t ws_size,
                              hipStream_t stream) {
    const float* x         = (const float*)d_in[0];
    const float* edge_attr = (const float*)d_in[1];
    const int*   ei        = (const int*)d_in[2];
    const int*   batch     = (const int*)d_in[3];
    const float* Wd        = (const float*)d_in[4];
    const float* fW1       = (const float*)d_in[5];
    const float* fb1       = (const float*)d_in[6];
    const float* fW2       = (const float*)d_in[7];
    const float* fb2       = (const float*)d_in[8];
    const float* av        = (const float*)d_in[9];
    const float* oW1       = (const float*)d_in[10];
    const float* ob1       = (const float*)d_in[11];
    const float* oW2       = (const float*)d_in[12];
    const float* ob2       = (const float*)d_in[13];
    const float* nW1       = (const float*)d_in[14];
    const float* nb1       = (const float*)d_in[15];
    const float* nW2       = (const float*)d_in[16];
    const float* nb2       = (const float*)d_in[17];
    float* out = (float*)d_out;

    const int N = in_sizes[0] / NODE_DIM;   // 50000
    const int E = in_sizes[2] / 2;          // 800000
    const int G = NGRAPH;

    char* base = (char*)d_ws;
    size_t pos = 0;
    auto alloc = [&](size_t bytes) -> void* {
        pos = (pos + 255) & ~(size_t)255;
        void* r = base + pos;
        pos += bytes;
        return r;
    };
    int* cnt  = (int*)alloc((size_t)N * 4);
    int* cur  = (int*)alloc((size_t)N * 4);
    int* gcnt = (int*)alloc((size_t)G * 4);
    size_t zero_bytes = pos;
    int* off  = (int*)alloc((size_t)(N + 1) * 4);
    int* goff = (int*)alloc((size_t)(G + 1) * 4);
    int* eidx = (int*)alloc((size_t)E * 4);
    int* srcp = (int*)alloc((size_t)E * 4);
    float* score = (float*)alloc((size_t)E * 4);
    float* hd    = (float*)alloc((size_t)N * NODE_DIM * 4);
    float* h     = (float*)alloc((size_t)N * NODE_DIM * 4);
    float* agg   = (float*)alloc((size_t)N * NODE_DIM * 4);
    float* t1    = (float*)alloc((size_t)N * HIDDEN * 4);
    float* pooled = (float*)alloc((size_t)G * NODE_DIM * 4);
    float* t2     = (float*)alloc((size_t)G * HIDDEN * 4);
    unsigned short* ew   = (unsigned short*)alloc((size_t)E * NODE_DIM * 2);
    unsigned short* W1sw = (unsigned short*)alloc((size_t)N_LAYERS * 8 * 64 * 8 * 2);
    unsigned short* W2sw = (unsigned short*)alloc((size_t)N_LAYERS * 16 * 64 * 8 * 2);
    (void)ws_size;

    const int* src = ei;
    const int* tgt = ei + E;

    hipMemsetAsync(d_ws, 0, zero_bytes, stream);
    hist_kernel<<<(E + 255) / 256, 256, 0, stream>>>(tgt, cnt, E);
    scan_kernel<<<1, 1024, 0, stream>>>(cnt, off, N);
    scatter_kernel<<<(E + 255) / 256, 256, 0, stream>>>(src, tgt, off, cur, eidx, srcp, E);
    hist_kernel<<<(N + 255) / 256, 256, 0, stream>>>(batch, gcnt, N);
    gscan_kernel<<<1, 128, 0, stream>>>(gcnt, goff, G);
    swizzle_w_kernel<<<N_LAYERS, 64, 0, stream>>>(fW1, fW2, W1sw, W2sw);
    hipMemcpyAsync(h, x, (size_t)N * NODE_DIM * 4, hipMemcpyDeviceToDevice, stream);

    for (int i = 0; i < N_LAYERS; ++i) {
        dense_kernel<NODE_DIM, NODE_DIM, false, false>
            <<<(N * NODE_DIM + 255) / 256, 256, 0, stream>>>(
                h, Wd + (size_t)i * NODE_DIM * NODE_DIM, nullptr, hd, N);
        edge_mfma_kernel<<<(E + 63) / 64, 256, 0, stream>>>(
            edge_attr, eidx, hd,
            W1sw + (size_t)i * 8 * 64 * 8, fb1 + (size_t)i * HIDDEN,
            W2sw + (size_t)i * 16 * 64 * 8, fb2 + (size_t)i * NODE_DIM,
            av + (size_t)i * NODE_DIM, srcp, ew, score, E);
        agg_kernel<<<(N + 3) / 4, 256, 0, stream>>>(ew, score, hd, srcp, off, agg, N);
        dense_kernel<NODE_DIM, HIDDEN, true, false>
            <<<(N * HIDDEN + 255) / 256, 256, 0, stream>>>(
                agg, oW1 + (size_t)i * NODE_DIM * HIDDEN, ob1 + (size_t)i * HIDDEN, t1, N);
        dense_kernel<HIDDEN, NODE_DIM, false, true>
            <<<(N * NODE_DIM + 255) / 256, 256, 0, stream>>>(
                t1, oW2 + (size_t)i * HIDDEN * NODE_DIM, ob2 + (size_t)i * NODE_DIM, h, N);
    }

    pool_kernel<<<G, 256, 0, stream>>>(h, goff, pooled);
    dense_kernel<NODE_DIM, HIDDEN, true, false>
        <<<(G * HIDDEN + 255) / 256, 256, 0, stream>>>(pooled, nW1, nb1, t2, G);
    dense_kernel<HIDDEN, OUT_DIM, false, false>
        <<<(G * OUT_DIM + 255) / 256, 256, 0, stream>>>(t2, nW2, nb2, out, G);
}

// Round 4
// 1261.222 us; speedup vs baseline: 4.0297x; 1.1249x over previous
//
#include <hip/hip_runtime.h>
#include <hip/hip_bf16.h>
#include <math.h>

#define NODE_DIM 64
#define EDGE_DIM 32
#define HIDDEN   128
#define OUT_DIM  32
#define N_LAYERS 3
#define NGRAPH   128

typedef __attribute__((ext_vector_type(8))) short bf16x8;
typedef __attribute__((ext_vector_type(4))) float f32x4;

__device__ __forceinline__ unsigned short f2bf(float f) {
    unsigned u = __float_as_uint(f);
    u = (u + 0x7fffu + ((u >> 16) & 1u)) >> 16;
    return (unsigned short)u;
}
__device__ __forceinline__ float bf2f(unsigned short h) {
    return __uint_as_float((unsigned)h << 16);
}
// tanh(x) = sign(x) * (1 - e) / (1 + e), e = exp(-2|x|)
__device__ __forceinline__ float fast_tanh(float x) {
    float ax = fabsf(x);
    float e = __expf(-2.f * ax);
    float r = __builtin_amdgcn_rcpf(1.f + e);
    float t = (1.f - e) * r;
    return __builtin_copysignf(t, x);
}

// ---------------------------------------------------------------------------
// Counting sort of edges by target node
// ---------------------------------------------------------------------------
__global__ void hist_kernel(const int* __restrict__ idx, int* __restrict__ cnt, int n) {
    int i = blockIdx.x * 256 + threadIdx.x;
    if (i < n) atomicAdd(&cnt[idx[i]], 1);
}

__global__ void scan_kernel(const int* __restrict__ c, int* __restrict__ o, int n) {
    __shared__ int sh[1024];
    int t = threadIdx.x;
    int chunk = (n + 1023) >> 10;
    int lo = t * chunk, hi = lo + chunk;
    if (hi > n) hi = n;
    if (lo > n) lo = n;
    int s = 0;
    for (int i = lo; i < hi; ++i) s += c[i];
    sh[t] = s;
    __syncthreads();
    for (int d = 1; d < 1024; d <<= 1) {
        int v = (t >= d) ? sh[t - d] : 0;
        __syncthreads();
        sh[t] += v;
        __syncthreads();
    }
    int run = sh[t] - s;
    for (int i = lo; i < hi; ++i) { o[i] = run; run += c[i]; }
    if (hi == n) o[n] = run;
}

__global__ void scatter_kernel(const int* __restrict__ src, const int* __restrict__ tgt,
                               const int* __restrict__ off, int* __restrict__ cur,
                               int* __restrict__ eidx, int* __restrict__ srcp, int n) {
    int e = blockIdx.x * 256 + threadIdx.x;
    if (e >= n) return;
    int t = tgt[e];
    int pos = off[t] + atomicAdd(&cur[t], 1);
    eidx[pos] = e;
    srcp[pos] = src[e];
}

__global__ void gscan_kernel(const int* __restrict__ c, int* __restrict__ o, int n) {
    __shared__ int sh[128];
    int t = threadIdx.x;
    int v = (t < n) ? c[t] : 0;
    sh[t] = v;
    __syncthreads();
    for (int d = 1; d < 128; d <<= 1) {
        int u = (t >= d) ? sh[t - d] : 0;
        __syncthreads();
        sh[t] += u;
        __syncthreads();
    }
    if (t < n) o[t] = sh[t] - v;
    if (t == n - 1) o[n] = sh[t];
}

// ---------------------------------------------------------------------------
// Swizzle W^T into MFMA A-operand fragments (bf16); block = layer.
// frag[(mt*(K/32)+s)*64 + L][j] = W[32s + 8q + j][16*mt + e]
// ---------------------------------------------------------------------------
__device__ __forceinline__ void swizzleA(const float* __restrict__ W,
                                         unsigned short* __restrict__ out,
                                         int K, int M, int L) {
    int e = L & 15, q = L >> 4;
    int nc = K >> 5;
    for (int mt = 0; mt < (M >> 4); ++mt)
        for (int s = 0; s < nc; ++s)
            for (int j = 0; j < 8; ++j)
                out[((mt * nc + s) * 64 + L) * 8 + j] =
                    f2bf(W[(32 * s + 8 * q + j) * M + 16 * mt + e]);
}

__global__ void swizzle_w_kernel(const float* __restrict__ fW1, const float* __restrict__ fW2,
                                 const float* __restrict__ oW1, const float* __restrict__ oW2,
                                 unsigned short* __restrict__ W1sw, unsigned short* __restrict__ W2sw,
                                 unsigned short* __restrict__ oW1sw, unsigned short* __restrict__ oW2sw) {
    int i = blockIdx.x;
    int L = threadIdx.x;
    swizzleA(fW1 + (size_t)i * EDGE_DIM * HIDDEN, W1sw + (size_t)i * 8 * 64 * 8, EDGE_DIM, HIDDEN, L);
    swizzleA(fW2 + (size_t)i * HIDDEN * NODE_DIM, W2sw + (size_t)i * 16 * 64 * 8, HIDDEN, NODE_DIM, L);
    swizzleA(oW1 + (size_t)i * NODE_DIM * HIDDEN, oW1sw + (size_t)i * 16 * 64 * 8, NODE_DIM, HIDDEN, L);
    swizzleA(oW2 + (size_t)i * HIDDEN * NODE_DIM, oW2sw + (size_t)i * 16 * 64 * 8, HIDDEN, NODE_DIM, L);
}

#define HSTRIDE 136  // shorts; 128 + 8 pad, keeps 16B alignment for ds_read_b128

// ---------------------------------------------------------------------------
// Persistent pipelined MFMA edge kernel: wave handles ~12 tiles of 16 edges.
// Next tile's eidx/srcp issued after GEMM1; next ea/hd gathers after GEMM2.
// ---------------------------------------------------------------------------
__global__ __launch_bounds__(256) void edge_mfma_kernel(
    const float* __restrict__ ea, const int* __restrict__ eidx,
    const float* __restrict__ hd,
    const unsigned short* __restrict__ W1sw, const float* __restrict__ b1,
    const unsigned short* __restrict__ W2sw, const float* __restrict__ b2,
    const float* __restrict__ av, const int* __restrict__ srcp,
    unsigned short* __restrict__ ew, float* __restrict__ score, int E) {
    __shared__ unsigned short Hl[4][16 * HSTRIDE];
    const int wave = threadIdx.x >> 6, lane = threadIdx.x & 63;
    const int e = lane & 15, q = lane >> 4;
    const int T = (E + 15) >> 4;
    const int nw = gridDim.x * 4;
    int t = blockIdx.x * 4 + wave;
    if (t >= T) return;
    unsigned short* hrow = &Hl[wave][e * HSTRIDE];

    // prologue gathers for first tile
    int pe = t * 16 + e;
    int peC = pe < E ? pe : E - 1;
    int esrc = eidx[peC];
    int sidx = srcp[peC];
    const float4* ear = (const float4*)(ea + (size_t)esrc * EDGE_DIM + q * 8);
    float4 a0 = ear[0], a1 = ear[1];
    const float* hb = hd + (size_t)sidx * NODE_DIM + 4 * q;
    float4 hh0 = *(const float4*)(hb);
    float4 hh1 = *(const float4*)(hb + 16);
    float4 hh2 = *(const float4*)(hb + 32);
    float4 hh3 = *(const float4*)(hb + 48);

    while (true) {
        int tn = t + nw;
        bool have_next = tn < T;   // wave-uniform
        int cur_pe = pe;

        union { bf16x8 v; unsigned short us[8]; } eau;
        eau.us[0] = f2bf(a0.x); eau.us[1] = f2bf(a0.y);
        eau.us[2] = f2bf(a0.z); eau.us[3] = f2bf(a0.w);
        eau.us[4] = f2bf(a1.x); eau.us[5] = f2bf(a1.y);
        eau.us[6] = f2bf(a1.z); eau.us[7] = f2bf(a1.w);
        bf16x8 eaf = eau.v;

        f32x4 c1[8];
#pragma unroll
        for (int tt = 0; tt < 8; ++tt) {
            bf16x8 a = *(const bf16x8*)(W1sw + (tt * 64 + lane) * 8);
            c1[tt] = __builtin_amdgcn_mfma_f32_16x16x32_bf16(a, eaf, (f32x4){0.f, 0.f, 0.f, 0.f}, 0, 0, 0);
        }

        // prefetch next tile's indices (latency hidden by tanh+LDS+GEMM2)
        int peN = 0, esrcN = 0, sidxN = 0;
        if (have_next) {
            peN = tn * 16 + e;
            int pc = peN < E ? peN : E - 1;
            esrcN = eidx[pc];
            sidxN = srcp[pc];
        }

#pragma unroll
        for (int tt = 0; tt < 8; ++tt) {
            float4 b = *(const float4*)(b1 + 16 * tt + 4 * q);
            unsigned h0 = f2bf(fast_tanh(c1[tt][0] + b.x));
            unsigned h1 = f2bf(fast_tanh(c1[tt][1] + b.y));
            unsigned h2 = f2bf(fast_tanh(c1[tt][2] + b.z));
            unsigned h3 = f2bf(fast_tanh(c1[tt][3] + b.w));
            uint2 pk;
            pk.x = h0 | (h1 << 16);
            pk.y = h2 | (h3 << 16);
            *(uint2*)(hrow + 16 * tt + 4 * q) = pk;
        }

        f32x4 c2[4] = {{0.f, 0.f, 0.f, 0.f}, {0.f, 0.f, 0.f, 0.f},
                       {0.f, 0.f, 0.f, 0.f}, {0.f, 0.f, 0.f, 0.f}};
#pragma unroll
        for (int s = 0; s < 4; ++s) {
            bf16x8 hf = *(const bf16x8*)(hrow + 32 * s + 8 * q);
#pragma unroll
            for (int nt = 0; nt < 4; ++nt) {
                bf16x8 a = *(const bf16x8*)(W2sw + ((nt * 4 + s) * 64 + lane) * 8);
                c2[nt] = __builtin_amdgcn_mfma_f32_16x16x32_bf16(a, hf, c2[nt], 0, 0, 0);
            }
        }

        // prefetch next tile's gathers (consumed next iteration)
        float4 a0n, a1n, h0n, h1n, h2n, h3n;
        if (have_next) {
            const float4* earn = (const float4*)(ea + (size_t)esrcN * EDGE_DIM + q * 8);
            a0n = earn[0]; a1n = earn[1];
            const float* hbn = hd + (size_t)sidxN * NODE_DIM + 4 * q;
            h0n = *(const float4*)(hbn);
            h1n = *(const float4*)(hbn + 16);
            h2n = *(const float4*)(hbn + 32);
            h3n = *(const float4*)(hbn + 48);
        }

        // epilogue
        float sc = 0.f;
        bool okst = cur_pe < E;
        float4 hhv[4] = {hh0, hh1, hh2, hh3};
#pragma unroll
        for (int nt = 0; nt < 4; ++nt) {
            float4 bb = *(const float4*)(b2 + 16 * nt + 4 * q);
            float4 vv = *(const float4*)(av + 16 * nt + 4 * q);
            float4 hh = hhv[nt];
            float e0 = c2[nt][0] + bb.x, e1 = c2[nt][1] + bb.y;
            float e2 = c2[nt][2] + bb.z, e3 = c2[nt][3] + bb.w;
            uint2 pk;
            pk.x = (unsigned)f2bf(e0) | ((unsigned)f2bf(e1) << 16);
            pk.y = (unsigned)f2bf(e2) | ((unsigned)f2bf(e3) << 16);
            if (okst) *(uint2*)(ew + (size_t)cur_pe * NODE_DIM + 16 * nt + 4 * q) = pk;
            sc += hh.x * e0 * vv.x + hh.y * e1 * vv.y + hh.z * e2 * vv.z + hh.w * e3 * vv.w;
        }
        sc += __shfl_xor(sc, 16, 64);
        sc += __shfl_xor(sc, 32, 64);
        if (q == 0 && okst) score[cur_pe] = sc;

        if (!have_next) break;
        t = tn; pe = peN;
        a0 = a0n; a1 = a1n;
        hh0 = h0n; hh1 = h1n; hh2 = h2n; hh3 = h3n;
    }
}

// ---------------------------------------------------------------------------
// Fused node out-MLP (MFMA): delta = tanh(agg@oW1+b1)@oW2+b2; h += delta
// Wave per 16 nodes.
// ---------------------------------------------------------------------------
__global__ __launch_bounds__(256) void node_mlp_kernel(
    const float* __restrict__ agg,
    const unsigned short* __restrict__ W1sw, const float* __restrict__ b1,
    const unsigned short* __restrict__ W2sw, const float* __restrict__ b2,
    float* __restrict__ h, int N) {
    __shared__ unsigned short Hl[4][16 * HSTRIDE];
    int wave = threadIdx.x >> 6, lane = threadIdx.x & 63;
    int e = lane & 15, q = lane >> 4;
    int n0 = (blockIdx.x * 4 + wave) * 16;
    if (n0 >= N) return;
    int ne = n0 + e;
    int neC = ne < N ? ne : N - 1;
    bool ok = ne < N;

    bf16x8 bfr[2];
#pragma unroll
    for (int s = 0; s < 2; ++s) {
        const float4* ar = (const float4*)(agg + (size_t)neC * NODE_DIM + 32 * s + 8 * q);
        float4 x0 = ar[0], x1 = ar[1];
        union { bf16x8 v; unsigned short us[8]; } u;
        u.us[0] = f2bf(x0.x); u.us[1] = f2bf(x0.y);
        u.us[2] = f2bf(x0.z); u.us[3] = f2bf(x0.w);
        u.us[4] = f2bf(x1.x); u.us[5] = f2bf(x1.y);
        u.us[6] = f2bf(x1.z); u.us[7] = f2bf(x1.w);
        bfr[s] = u.v;
    }

    f32x4 c1[8];
#pragma unroll
    for (int t = 0; t < 8; ++t) {
        bf16x8 a0 = *(const bf16x8*)(W1sw + ((t * 2 + 0) * 64 + lane) * 8);
        bf16x8 a1 = *(const bf16x8*)(W1sw + ((t * 2 + 1) * 64 + lane) * 8);
        c1[t] = __builtin_amdgcn_mfma_f32_16x16x32_bf16(a0, bfr[0], (f32x4){0.f, 0.f, 0.f, 0.f}, 0, 0, 0);
        c1[t] = __builtin_amdgcn_mfma_f32_16x16x32_bf16(a1, bfr[1], c1[t], 0, 0, 0);
    }

    unsigned short* hrow = &Hl[wave][e * HSTRIDE];
#pragma unroll
    for (int t = 0; t < 8; ++t) {
        float4 b = *(const float4*)(b1 + 16 * t + 4 * q);
        unsigned h0 = f2bf(fast_tanh(c1[t][0] + b.x));
        unsigned h1 = f2bf(fast_tanh(c1[t][1] + b.y));
        unsigned h2 = f2bf(fast_tanh(c1[t][2] + b.z));
        unsigned h3 = f2bf(fast_tanh(c1[t][3] + b.w));
        uint2 pk;
        pk.x = h0 | (h1 << 16);
        pk.y = h2 | (h3 << 16);
        *(uint2*)(hrow + 16 * t + 4 * q) = pk;
    }

    f32x4 c2[4] = {{0.f, 0.f, 0.f, 0.f}, {0.f, 0.f, 0.f, 0.f},
                   {0.f, 0.f, 0.f, 0.f}, {0.f, 0.f, 0.f, 0.f}};
#pragma unroll
    for (int s = 0; s < 4; ++s) {
        bf16x8 hf = *(const bf16x8*)(hrow + 32 * s + 8 * q);
#pragma unroll
        for (int nt = 0; nt < 4; ++nt) {
            bf16x8 a = *(const bf16x8*)(W2sw + ((nt * 4 + s) * 64 + lane) * 8);
            c2[nt] = __builtin_amdgcn_mfma_f32_16x16x32_bf16(a, hf, c2[nt], 0, 0, 0);
        }
    }

    if (ok) {
#pragma unroll
        for (int nt = 0; nt < 4; ++nt) {
            float4 bb = *(const float4*)(b2 + 16 * nt + 4 * q);
            float4* hp = (float4*)(h + (size_t)ne * NODE_DIM + 16 * nt + 4 * q);
            float4 hv = *hp;
            hv.x += c2[nt][0] + bb.x;
            hv.y += c2[nt][1] + bb.y;
            hv.z += c2[nt][2] + bb.z;
            hv.w += c2[nt][3] + bb.w;
            *hp = hv;
        }
    }
}

// ---------------------------------------------------------------------------
// Generic dense layer (fp32): hd and final output MLP
// ---------------------------------------------------------------------------
template <int K, int M, bool ACT, bool RESID>
__global__ __launch_bounds__(256) void dense_kernel(
    const float* __restrict__ X, const float* __restrict__ W,
    const float* __restrict__ bias, float* __restrict__ Y, int rows) {
    int tid = blockIdx.x * 256 + threadIdx.x;
    int row = tid / M;
    int d = tid - row * M;
    if (row >= rows) return;
    if (M >= 64) row = __builtin_amdgcn_readfirstlane(row);
    const float* __restrict__ x = X + (size_t)row * K;
    float acc = bias ? bias[d] : 0.f;
#pragma unroll
    for (int k = 0; k < K; ++k) acc += x[k] * W[k * M + d];
    if (ACT) acc = fast_tanh(acc);
    if (RESID) acc += Y[(size_t)row * M + d];
    Y[(size_t)row * M + d] = acc;
}

// ---------------------------------------------------------------------------
// Aggregation: wave per node; 8 edges x 8 dim-groups per iteration
// ---------------------------------------------------------------------------
__global__ __launch_bounds__(256) void agg_kernel(
    const unsigned short* __restrict__ ew, const float* __restrict__ score,
    const float* __restrict__ hd, const int* __restrict__ srcp,
    const int* __restrict__ off, float* __restrict__ agg, int n) {
    int tid = blockIdx.x * 256 + threadIdx.x;
    int wid = tid >> 6;
    int lane = threadIdx.x & 63;
    if (wid >= n) return;
    wid = __builtin_amdgcn_readfirstlane(wid);
    int o0 = off[wid], o1 = off[wid + 1];
    int g = lane >> 3, s = lane & 7;
    if (o1 <= o0) {
        if (g == 0) {
            float4 z = {0.f, 0.f, 0.f, 0.f};
            float4* dst = (float4*)(agg + (size_t)wid * NODE_DIM + s * 8);
            dst[0] = z; dst[1] = z;
        }
        return;
    }
    float m = -INFINITY;
    for (int p = o0 + lane; p < o1; p += 64) m = fmaxf(m, score[p]);
#pragma unroll
    for (int t = 32; t; t >>= 1) m = fmaxf(m, __shfl_xor(m, t, 64));
    float dsum = 0.f;
    for (int p = o0 + lane; p < o1; p += 64) dsum += __expf(score[p] - m);
#pragma unroll
    for (int t = 32; t; t >>= 1) dsum += __shfl_xor(dsum, t, 64);

    float acc[8] = {0.f, 0.f, 0.f, 0.f, 0.f, 0.f, 0.f, 0.f};
    for (int p = o0; p < o1; p += 8) {
        int pe = p + g;
        int pc = (pe < o1) ? pe : (o1 - 1);
        float w = (pe < o1) ? __expf(score[pc] - m) : 0.f;
        int sidx = srcp[pc];
        union { bf16x8 v; unsigned short us[8]; } eu;
        eu.v = *(const bf16x8*)(ew + (size_t)pc * NODE_DIM + s * 8);
        const float4* hr = (const float4*)(hd + (size_t)sidx * NODE_DIM + s * 8);
        float4 h0 = hr[0], h1 = hr[1];
        acc[0] += w * h0.x * bf2f(eu.us[0]);
        acc[1] += w * h0.y * bf2f(eu.us[1]);
        acc[2] += w * h0.z * bf2f(eu.us[2]);
        acc[3] += w * h0.w * bf2f(eu.us[3]);
        acc[4] += w * h1.x * bf2f(eu.us[4]);
        acc[5] += w * h1.y * bf2f(eu.us[5]);
        acc[6] += w * h1.z * bf2f(eu.us[6]);
        acc[7] += w * h1.w * bf2f(eu.us[7]);
    }
#pragma unroll
    for (int j = 0; j < 8; ++j) {
        acc[j] += __shfl_xor(acc[j], 8, 64);
        acc[j] += __shfl_xor(acc[j], 16, 64);
        acc[j] += __shfl_xor(acc[j], 32, 64);
    }
    if (g == 0) {
        float inv = __builtin_amdgcn_rcpf(dsum);
        inv = inv * (2.f - dsum * inv);
        float4 r0 = {acc[0] * inv, acc[1] * inv, acc[2] * inv, acc[3] * inv};
        float4 r1 = {acc[4] * inv, acc[5] * inv, acc[6] * inv, acc[7] * inv};
        float4* dst = (float4*)(agg + (size_t)wid * NODE_DIM + s * 8);
        dst[0] = r0; dst[1] = r1;
    }
}

// ---------------------------------------------------------------------------
// Mean pool per graph: 4 waves per graph + LDS reduce
// ---------------------------------------------------------------------------
__global__ __launch_bounds__(256) void pool_kernel(const float* __restrict__ h,
                                                   const int* __restrict__ goff,
                                                   float* __restrict__ pooled) {
    __shared__ float sh[4][NODE_DIM];
    int g = blockIdx.x;
    int w = threadIdx.x >> 6, d = threadIdx.x & 63;
    int o0 = goff[g], o1 = goff[g + 1];
    float acc = 0.f;
    for (int n = o0 + w; n < o1; n += 4) acc += h[(size_t)n * NODE_DIM + d];
    sh[w][d] = acc;
    __syncthreads();
    if (w == 0) {
        float sum = sh[0][d] + sh[1][d] + sh[2][d] + sh[3][d];
        int c = o1 - o0;
        if (c < 1) c = 1;
        pooled[g * NODE_DIM + d] = sum / (float)c;
    }
}

// ---------------------------------------------------------------------------
extern "C" void kernel_launch(void* const* d_in, const int* in_sizes, int n_in,
                              void* d_out, int out_size, void* d_ws, size_t ws_size,
                              hipStream_t stream) {
    const float* x         = (const float*)d_in[0];
    const float* edge_attr = (const float*)d_in[1];
    const int*   ei        = (const int*)d_in[2];
    const int*   batch     = (const int*)d_in[3];
    const float* Wd        = (const float*)d_in[4];
    const float* fW1       = (const float*)d_in[5];
    const float* fb1       = (const float*)d_in[6];
    const float* fW2       = (const float*)d_in[7];
    const float* fb2       = (const float*)d_in[8];
    const float* av        = (const float*)d_in[9];
    const float* oW1       = (const float*)d_in[10];
    const float* ob1       = (const float*)d_in[11];
    const float* oW2       = (const float*)d_in[12];
    const float* ob2       = (const float*)d_in[13];
    const float* nW1       = (const float*)d_in[14];
    const float* nb1       = (const float*)d_in[15];
    const float* nW2       = (const float*)d_in[16];
    const float* nb2       = (const float*)d_in[17];
    float* out = (float*)d_out;

    const int N = in_sizes[0] / NODE_DIM;   // 50000
    const int E = in_sizes[2] / 2;          // 800000
    const int G = NGRAPH;

    char* base = (char*)d_ws;
    size_t pos = 0;
    auto alloc = [&](size_t bytes) -> void* {
        pos = (pos + 255) & ~(size_t)255;
        void* r = base + pos;
        pos += bytes;
        return r;
    };
    int* cnt  = (int*)alloc((size_t)N * 4);
    int* cur  = (int*)alloc((size_t)N * 4);
    int* gcnt = (int*)alloc((size_t)G * 4);
    size_t zero_bytes = pos;
    int* off  = (int*)alloc((size_t)(N + 1) * 4);
    int* goff = (int*)alloc((size_t)(G + 1) * 4);
    int* eidx = (int*)alloc((size_t)E * 4);
    int* srcp = (int*)alloc((size_t)E * 4);
    float* score = (float*)alloc((size_t)E * 4);
    float* hd    = (float*)alloc((size_t)N * NODE_DIM * 4);
    float* h     = (float*)alloc((size_t)N * NODE_DIM * 4);
    float* agg   = (float*)alloc((size_t)N * NODE_DIM * 4);
    float* pooled = (float*)alloc((size_t)G * NODE_DIM * 4);
    float* t2     = (float*)alloc((size_t)G * HIDDEN * 4);
    unsigned short* ew    = (unsigned short*)alloc((size_t)E * NODE_DIM * 2);
    unsigned short* W1sw  = (unsigned short*)alloc((size_t)N_LAYERS * 8 * 64 * 8 * 2);
    unsigned short* W2sw  = (unsigned short*)alloc((size_t)N_LAYERS * 16 * 64 * 8 * 2);
    unsigned short* oW1sw = (unsigned short*)alloc((size_t)N_LAYERS * 16 * 64 * 8 * 2);
    unsigned short* oW2sw = (unsigned short*)alloc((size_t)N_LAYERS * 16 * 64 * 8 * 2);
    (void)ws_size;

    const int* src = ei;
    const int* tgt = ei + E;

    hipMemsetAsync(d_ws, 0, zero_bytes, stream);
    hist_kernel<<<(E + 255) / 256, 256, 0, stream>>>(tgt, cnt, E);
    scan_kernel<<<1, 1024, 0, stream>>>(cnt, off, N);
    scatter_kernel<<<(E + 255) / 256, 256, 0, stream>>>(src, tgt, off, cur, eidx, srcp, E);
    hist_kernel<<<(N + 255) / 256, 256, 0, stream>>>(batch, gcnt, N);
    gscan_kernel<<<1, 128, 0, stream>>>(gcnt, goff, G);
    swizzle_w_kernel<<<N_LAYERS, 64, 0, stream>>>(fW1, fW2, oW1, oW2, W1sw, W2sw, oW1sw, oW2sw);
    hipMemcpyAsync(h, x, (size_t)N * NODE_DIM * 4, hipMemcpyDeviceToDevice, stream);

    const int node_tiles = (N + 15) / 16;
    for (int i = 0; i < N_LAYERS; ++i) {
        dense_kernel<NODE_DIM, NODE_DIM, false, false>
            <<<(N * NODE_DIM + 255) / 256, 256, 0, stream>>>(
                h, Wd + (size_t)i * NODE_DIM * NODE_DIM, nullptr, hd, N);
        edge_mfma_kernel<<<1024, 256, 0, stream>>>(
            edge_attr, eidx, hd,
            W1sw + (size_t)i * 8 * 64 * 8, fb1 + (size_t)i * HIDDEN,
            W2sw + (size_t)i * 16 * 64 * 8, fb2 + (size_t)i * NODE_DIM,
            av + (size_t)i * NODE_DIM, srcp, ew, score, E);
        agg_kernel<<<(N + 3) / 4, 256, 0, stream>>>(ew, score, hd, srcp, off, agg, N);
        node_mlp_kernel<<<(node_tiles + 3) / 4, 256, 0, stream>>>(
            agg,
            oW1sw + (size_t)i * 16 * 64 * 8, ob1 + (size_t)i * HIDDEN,
            oW2sw + (size_t)i * 16 * 64 * 8, ob2 + (size_t)i * NODE_DIM,
            h, N);
    }

    pool_kernel<<<G, 256, 0, stream>>>(h, goff, pooled);
    dense_kernel<NODE_DIM, HIDDEN, true, false>
        <<<(G * HIDDEN + 255) / 256, 256, 0, stream>>>(pooled, nW1, nb1, t2, G);
    dense_kernel<HIDDEN, OUT_DIM, false, false>
        <<<(G * OUT_DIM + 255) / 256, 256, 0, stream>>>(t2, nW2, nb2, out, G);
}

// Round 5
// 1171.363 us; speedup vs baseline: 4.3389x; 1.0767x over previous
//
#include <hip/hip_runtime.h>
#include <hip/hip_bf16.h>
#include <math.h>

#define NODE_DIM 64
#define EDGE_DIM 32
#define HIDDEN   128
#define OUT_DIM  32
#define N_LAYERS 3
#define NGRAPH   128

typedef __attribute__((ext_vector_type(8))) short bf16x8;
typedef __attribute__((ext_vector_type(4))) float f32x4;

__device__ __forceinline__ unsigned short f2bf(float f) {
    unsigned u = __float_as_uint(f);
    u = (u + 0x7fffu + ((u >> 16) & 1u)) >> 16;
    return (unsigned short)u;
}
__device__ __forceinline__ float bf2f(unsigned short h) {
    return __uint_as_float((unsigned)h << 16);
}
// tanh(x) = sign(x) * (1 - e) / (1 + e), e = exp(-2|x|)
__device__ __forceinline__ float fast_tanh(float x) {
    float ax = fabsf(x);
    float e = __expf(-2.f * ax);
    float r = __builtin_amdgcn_rcpf(1.f + e);
    float t = (1.f - e) * r;
    return __builtin_copysignf(t, x);
}

// ---------------------------------------------------------------------------
// Counting sort of edges by target node
// ---------------------------------------------------------------------------
__global__ void hist_kernel(const int* __restrict__ idx, int* __restrict__ cnt, int n) {
    int i = blockIdx.x * 256 + threadIdx.x;
    if (i < n) atomicAdd(&cnt[idx[i]], 1);
}

__global__ void scan_kernel(const int* __restrict__ c, int* __restrict__ o, int n) {
    __shared__ int sh[1024];
    int t = threadIdx.x;
    int chunk = (n + 1023) >> 10;
    int lo = t * chunk, hi = lo + chunk;
    if (hi > n) hi = n;
    if (lo > n) lo = n;
    int s = 0;
    for (int i = lo; i < hi; ++i) s += c[i];
    sh[t] = s;
    __syncthreads();
    for (int d = 1; d < 1024; d <<= 1) {
        int v = (t >= d) ? sh[t - d] : 0;
        __syncthreads();
        sh[t] += v;
        __syncthreads();
    }
    int run = sh[t] - s;
    for (int i = lo; i < hi; ++i) { o[i] = run; run += c[i]; }
    if (hi == n) o[n] = run;
}

__global__ void scatter_kernel(const int* __restrict__ src, const int* __restrict__ tgt,
                               const int* __restrict__ off, int* __restrict__ cur,
                               int* __restrict__ eidx, int* __restrict__ srcp, int n) {
    int e = blockIdx.x * 256 + threadIdx.x;
    if (e >= n) return;
    int t = tgt[e];
    int pos = off[t] + atomicAdd(&cur[t], 1);
    eidx[pos] = e;
    srcp[pos] = src[e];
}

__global__ void gscan_kernel(const int* __restrict__ c, int* __restrict__ o, int n) {
    __shared__ int sh[128];
    int t = threadIdx.x;
    int v = (t < n) ? c[t] : 0;
    sh[t] = v;
    __syncthreads();
    for (int d = 1; d < 128; d <<= 1) {
        int u = (t >= d) ? sh[t - d] : 0;
        __syncthreads();
        sh[t] += u;
        __syncthreads();
    }
    if (t < n) o[t] = sh[t] - v;
    if (t == n - 1) o[n] = sh[t];
}

// ---------------------------------------------------------------------------
// Permute+convert edge_attr to bf16 in target-sorted order (coalesced writes)
// ---------------------------------------------------------------------------
__global__ __launch_bounds__(256) void perm_ea_kernel(
    const float* __restrict__ ea, const int* __restrict__ eidx,
    unsigned short* __restrict__ out, int E) {
    int p = blockIdx.x * 256 + threadIdx.x;
    if (p >= E) return;
    int e = eidx[p];
    const float4* r = (const float4*)(ea + (size_t)e * EDGE_DIM);
    union { unsigned short us[EDGE_DIM]; uint4 u4[EDGE_DIM / 8]; } tmp;
#pragma unroll
    for (int q = 0; q < EDGE_DIM / 4; ++q) {
        float4 v = r[q];
        tmp.us[4 * q]     = f2bf(v.x);
        tmp.us[4 * q + 1] = f2bf(v.y);
        tmp.us[4 * q + 2] = f2bf(v.z);
        tmp.us[4 * q + 3] = f2bf(v.w);
    }
    uint4* o = (uint4*)(out + (size_t)p * EDGE_DIM);
#pragma unroll
    for (int k = 0; k < EDGE_DIM / 8; ++k) o[k] = tmp.u4[k];
}

// ---------------------------------------------------------------------------
// Swizzle W^T into MFMA A-operand fragments (bf16); block = layer.
// frag[(mt*(K/32)+s)*64 + L][j] = W[32s + 8q + j][16*mt + e]
// ---------------------------------------------------------------------------
__device__ __forceinline__ void swizzleA(const float* __restrict__ W,
                                         unsigned short* __restrict__ out,
                                         int K, int M, int L) {
    int e = L & 15, q = L >> 4;
    int nc = K >> 5;
    for (int mt = 0; mt < (M >> 4); ++mt)
        for (int s = 0; s < nc; ++s)
            for (int j = 0; j < 8; ++j)
                out[((mt * nc + s) * 64 + L) * 8 + j] =
                    f2bf(W[(32 * s + 8 * q + j) * M + 16 * mt + e]);
}

__global__ void swizzle_w_kernel(const float* __restrict__ fW1, const float* __restrict__ fW2,
                                 const float* __restrict__ oW1, const float* __restrict__ oW2,
                                 unsigned short* __restrict__ W1sw, unsigned short* __restrict__ W2sw,
                                 unsigned short* __restrict__ oW1sw, unsigned short* __restrict__ oW2sw) {
    int i = blockIdx.x;
    int L = threadIdx.x;
    swizzleA(fW1 + (size_t)i * EDGE_DIM * HIDDEN, W1sw + (size_t)i * 8 * 64 * 8, EDGE_DIM, HIDDEN, L);
    swizzleA(fW2 + (size_t)i * HIDDEN * NODE_DIM, W2sw + (size_t)i * 16 * 64 * 8, HIDDEN, NODE_DIM, L);
    swizzleA(oW1 + (size_t)i * NODE_DIM * HIDDEN, oW1sw + (size_t)i * 16 * 64 * 8, NODE_DIM, HIDDEN, L);
    swizzleA(oW2 + (size_t)i * HIDDEN * NODE_DIM, oW2sw + (size_t)i * 16 * 64 * 8, HIDDEN, NODE_DIM, L);
}

#define HSTRIDE 136  // shorts; 128 + 8 pad, keeps 16B alignment for ds_read_b128

// ---------------------------------------------------------------------------
// MFMA edge kernel (one-shot, R2 structure + fast_tanh): wave per 16 edges.
// B-frag = one coalesced 16B load from pre-permuted bf16 ea_p.
// GEMM1^T -> tanh -> per-wave LDS -> GEMM2^T -> ew/score epilogue.
// ---------------------------------------------------------------------------
__global__ __launch_bounds__(256) void edge_mfma_kernel(
    const unsigned short* __restrict__ ea_p, const float* __restrict__ hd,
    const unsigned short* __restrict__ W1sw, const float* __restrict__ b1,
    const unsigned short* __restrict__ W2sw, const float* __restrict__ b2,
    const float* __restrict__ av, const int* __restrict__ srcp,
    unsigned short* __restrict__ ew, float* __restrict__ score, int E) {
    __shared__ unsigned short Hl[4][16 * HSTRIDE];
    int wave = threadIdx.x >> 6, lane = threadIdx.x & 63;
    int e = lane & 15, q = lane >> 4;
    int p0 = blockIdx.x * 64 + wave * 16;
    if (p0 >= E) return;

    bf16x8 eaf = *(const bf16x8*)(ea_p + (size_t)(p0 + e) * EDGE_DIM + q * 8);

    f32x4 c1[8];
#pragma unroll
    for (int t = 0; t < 8; ++t) {
        bf16x8 a = *(const bf16x8*)(W1sw + (t * 64 + lane) * 8);
        c1[t] = __builtin_amdgcn_mfma_f32_16x16x32_bf16(a, eaf, (f32x4){0.f, 0.f, 0.f, 0.f}, 0, 0, 0);
    }

    unsigned short* hrow = &Hl[wave][e * HSTRIDE];
#pragma unroll
    for (int t = 0; t < 8; ++t) {
        float4 b = *(const float4*)(b1 + 16 * t + 4 * q);
        unsigned h0 = f2bf(fast_tanh(c1[t][0] + b.x));
        unsigned h1 = f2bf(fast_tanh(c1[t][1] + b.y));
        unsigned h2 = f2bf(fast_tanh(c1[t][2] + b.z));
        unsigned h3 = f2bf(fast_tanh(c1[t][3] + b.w));
        uint2 pk;
        pk.x = h0 | (h1 << 16);
        pk.y = h2 | (h3 << 16);
        *(uint2*)(hrow + 16 * t + 4 * q) = pk;  // ds_write_b64
    }

    f32x4 c2[4] = {{0.f, 0.f, 0.f, 0.f}, {0.f, 0.f, 0.f, 0.f},
                   {0.f, 0.f, 0.f, 0.f}, {0.f, 0.f, 0.f, 0.f}};
#pragma unroll
    for (int s = 0; s < 4; ++s) {
        bf16x8 hf = *(const bf16x8*)(hrow + 32 * s + 8 * q);
#pragma unroll
        for (int nt = 0; nt < 4; ++nt) {
            bf16x8 a = *(const bf16x8*)(W2sw + ((nt * 4 + s) * 64 + lane) * 8);
            c2[nt] = __builtin_amdgcn_mfma_f32_16x16x32_bf16(a, hf, c2[nt], 0, 0, 0);
        }
    }

    int sidx = srcp[p0 + e];
    float sc = 0.f;
#pragma unroll
    for (int nt = 0; nt < 4; ++nt) {
        float4 bb = *(const float4*)(b2 + 16 * nt + 4 * q);
        float4 vv = *(const float4*)(av + 16 * nt + 4 * q);
        float4 hh = *(const float4*)(hd + (size_t)sidx * NODE_DIM + 16 * nt + 4 * q);
        float e0 = c2[nt][0] + bb.x, e1 = c2[nt][1] + bb.y;
        float e2 = c2[nt][2] + bb.z, e3 = c2[nt][3] + bb.w;
        uint2 pk;
        pk.x = (unsigned)f2bf(e0) | ((unsigned)f2bf(e1) << 16);
        pk.y = (unsigned)f2bf(e2) | ((unsigned)f2bf(e3) << 16);
        *(uint2*)(ew + (size_t)(p0 + e) * NODE_DIM + 16 * nt + 4 * q) = pk;
        sc += hh.x * e0 * vv.x + hh.y * e1 * vv.y + hh.z * e2 * vv.z + hh.w * e3 * vv.w;
    }
    sc += __shfl_xor(sc, 16, 64);
    sc += __shfl_xor(sc, 32, 64);
    if (q == 0) score[p0 + e] = sc;
}

// ---------------------------------------------------------------------------
// Fused node out-MLP (MFMA): delta = tanh(agg@oW1+b1)@oW2+b2; h += delta
// Wave per 16 nodes.
// ---------------------------------------------------------------------------
__global__ __launch_bounds__(256) void node_mlp_kernel(
    const float* __restrict__ agg,
    const unsigned short* __restrict__ W1sw, const float* __restrict__ b1,
    const unsigned short* __restrict__ W2sw, const float* __restrict__ b2,
    float* __restrict__ h, int N) {
    __shared__ unsigned short Hl[4][16 * HSTRIDE];
    int wave = threadIdx.x >> 6, lane = threadIdx.x & 63;
    int e = lane & 15, q = lane >> 4;
    int n0 = (blockIdx.x * 4 + wave) * 16;
    if (n0 >= N) return;
    int ne = n0 + e;
    int neC = ne < N ? ne : N - 1;
    bool ok = ne < N;

    bf16x8 bfr[2];
#pragma unroll
    for (int s = 0; s < 2; ++s) {
        const float4* ar = (const float4*)(agg + (size_t)neC * NODE_DIM + 32 * s + 8 * q);
        float4 x0 = ar[0], x1 = ar[1];
        union { bf16x8 v; unsigned short us[8]; } u;
        u.us[0] = f2bf(x0.x); u.us[1] = f2bf(x0.y);
        u.us[2] = f2bf(x0.z); u.us[3] = f2bf(x0.w);
        u.us[4] = f2bf(x1.x); u.us[5] = f2bf(x1.y);
        u.us[6] = f2bf(x1.z); u.us[7] = f2bf(x1.w);
        bfr[s] = u.v;
    }

    f32x4 c1[8];
#pragma unroll
    for (int t = 0; t < 8; ++t) {
        bf16x8 a0 = *(const bf16x8*)(W1sw + ((t * 2 + 0) * 64 + lane) * 8);
        bf16x8 a1 = *(const bf16x8*)(W1sw + ((t * 2 + 1) * 64 + lane) * 8);
        c1[t] = __builtin_amdgcn_mfma_f32_16x16x32_bf16(a0, bfr[0], (f32x4){0.f, 0.f, 0.f, 0.f}, 0, 0, 0);
        c1[t] = __builtin_amdgcn_mfma_f32_16x16x32_bf16(a1, bfr[1], c1[t], 0, 0, 0);
    }

    unsigned short* hrow = &Hl[wave][e * HSTRIDE];
#pragma unroll
    for (int t = 0; t < 8; ++t) {
        float4 b = *(const float4*)(b1 + 16 * t + 4 * q);
        unsigned h0 = f2bf(fast_tanh(c1[t][0] + b.x));
        unsigned h1 = f2bf(fast_tanh(c1[t][1] + b.y));
        unsigned h2 = f2bf(fast_tanh(c1[t][2] + b.z));
        unsigned h3 = f2bf(fast_tanh(c1[t][3] + b.w));
        uint2 pk;
        pk.x = h0 | (h1 << 16);
        pk.y = h2 | (h3 << 16);
        *(uint2*)(hrow + 16 * t + 4 * q) = pk;
    }

    f32x4 c2[4] = {{0.f, 0.f, 0.f, 0.f}, {0.f, 0.f, 0.f, 0.f},
                   {0.f, 0.f, 0.f, 0.f}, {0.f, 0.f, 0.f, 0.f}};
#pragma unroll
    for (int s = 0; s < 4; ++s) {
        bf16x8 hf = *(const bf16x8*)(hrow + 32 * s + 8 * q);
#pragma unroll
        for (int nt = 0; nt < 4; ++nt) {
            bf16x8 a = *(const bf16x8*)(W2sw + ((nt * 4 + s) * 64 + lane) * 8);
            c2[nt] = __builtin_amdgcn_mfma_f32_16x16x32_bf16(a, hf, c2[nt], 0, 0, 0);
        }
    }

    if (ok) {
#pragma unroll
        for (int nt = 0; nt < 4; ++nt) {
            float4 bb = *(const float4*)(b2 + 16 * nt + 4 * q);
            float4* hp = (float4*)(h + (size_t)ne * NODE_DIM + 16 * nt + 4 * q);
            float4 hv = *hp;
            hv.x += c2[nt][0] + bb.x;
            hv.y += c2[nt][1] + bb.y;
            hv.z += c2[nt][2] + bb.z;
            hv.w += c2[nt][3] + bb.w;
            *hp = hv;
        }
    }
}

// ---------------------------------------------------------------------------
// Generic dense layer (fp32): hd and final output MLP
// ---------------------------------------------------------------------------
template <int K, int M, bool ACT, bool RESID>
__global__ __launch_bounds__(256) void dense_kernel(
    const float* __restrict__ X, const float* __restrict__ W,
    const float* __restrict__ bias, float* __restrict__ Y, int rows) {
    int tid = blockIdx.x * 256 + threadIdx.x;
    int row = tid / M;
    int d = tid - row * M;
    if (row >= rows) return;
    if (M >= 64) row = __builtin_amdgcn_readfirstlane(row);
    const float* __restrict__ x = X + (size_t)row * K;
    float acc = bias ? bias[d] : 0.f;
#pragma unroll
    for (int k = 0; k < K; ++k) acc += x[k] * W[k * M + d];
    if (ACT) acc = fast_tanh(acc);
    if (RESID) acc += Y[(size_t)row * M + d];
    Y[(size_t)row * M + d] = acc;
}

// ---------------------------------------------------------------------------
// Aggregation: wave per node; 8 edges x 8 dim-groups per iteration
// ---------------------------------------------------------------------------
__global__ __launch_bounds__(256) void agg_kernel(
    const unsigned short* __restrict__ ew, const float* __restrict__ score,
    const float* __restrict__ hd, const int* __restrict__ srcp,
    const int* __restrict__ off, float* __restrict__ agg, int n) {
    int tid = blockIdx.x * 256 + threadIdx.x;
    int wid = tid >> 6;
    int lane = threadIdx.x & 63;
    if (wid >= n) return;
    wid = __builtin_amdgcn_readfirstlane(wid);
    int o0 = off[wid], o1 = off[wid + 1];
    int g = lane >> 3, s = lane & 7;
    if (o1 <= o0) {
        if (g == 0) {
            float4 z = {0.f, 0.f, 0.f, 0.f};
            float4* dst = (float4*)(agg + (size_t)wid * NODE_DIM + s * 8);
            dst[0] = z; dst[1] = z;
        }
        return;
    }
    float m = -INFINITY;
    for (int p = o0 + lane; p < o1; p += 64) m = fmaxf(m, score[p]);
#pragma unroll
    for (int t = 32; t; t >>= 1) m = fmaxf(m, __shfl_xor(m, t, 64));
    float dsum = 0.f;
    for (int p = o0 + lane; p < o1; p += 64) dsum += __expf(score[p] - m);
#pragma unroll
    for (int t = 32; t; t >>= 1) dsum += __shfl_xor(dsum, t, 64);

    float acc[8] = {0.f, 0.f, 0.f, 0.f, 0.f, 0.f, 0.f, 0.f};
    for (int p = o0; p < o1; p += 8) {
        int pe = p + g;
        int pc = (pe < o1) ? pe : (o1 - 1);
        float w = (pe < o1) ? __expf(score[pc] - m) : 0.f;
        int sidx = srcp[pc];
        union { bf16x8 v; unsigned short us[8]; } eu;
        eu.v = *(const bf16x8*)(ew + (size_t)pc * NODE_DIM + s * 8);
        const float4* hr = (const float4*)(hd + (size_t)sidx * NODE_DIM + s * 8);
        float4 h0 = hr[0], h1 = hr[1];
        acc[0] += w * h0.x * bf2f(eu.us[0]);
        acc[1] += w * h0.y * bf2f(eu.us[1]);
        acc[2] += w * h0.z * bf2f(eu.us[2]);
        acc[3] += w * h0.w * bf2f(eu.us[3]);
        acc[4] += w * h1.x * bf2f(eu.us[4]);
        acc[5] += w * h1.y * bf2f(eu.us[5]);
        acc[6] += w * h1.z * bf2f(eu.us[6]);
        acc[7] += w * h1.w * bf2f(eu.us[7]);
    }
#pragma unroll
    for (int j = 0; j < 8; ++j) {
        acc[j] += __shfl_xor(acc[j], 8, 64);
        acc[j] += __shfl_xor(acc[j], 16, 64);
        acc[j] += __shfl_xor(acc[j], 32, 64);
    }
    if (g == 0) {
        float inv = __builtin_amdgcn_rcpf(dsum);
        inv = inv * (2.f - dsum * inv);
        float4 r0 = {acc[0] * inv, acc[1] * inv, acc[2] * inv, acc[3] * inv};
        float4 r1 = {acc[4] * inv, acc[5] * inv, acc[6] * inv, acc[7] * inv};
        float4* dst = (float4*)(agg + (size_t)wid * NODE_DIM + s * 8);
        dst[0] = r0; dst[1] = r1;
    }
}

// ---------------------------------------------------------------------------
// Mean pool per graph: 4 waves per graph + LDS reduce
// ---------------------------------------------------------------------------
__global__ __launch_bounds__(256) void pool_kernel(const float* __restrict__ h,
                                                   const int* __restrict__ goff,
                                                   float* __restrict__ pooled) {
    __shared__ float sh[4][NODE_DIM];
    int g = blockIdx.x;
    int w = threadIdx.x >> 6, d = threadIdx.x & 63;
    int o0 = goff[g], o1 = goff[g + 1];
    float acc = 0.f;
    for (int n = o0 + w; n < o1; n += 4) acc += h[(size_t)n * NODE_DIM + d];
    sh[w][d] = acc;
    __syncthreads();
    if (w == 0) {
        float sum = sh[0][d] + sh[1][d] + sh[2][d] + sh[3][d];
        int c = o1 - o0;
        if (c < 1) c = 1;
        pooled[g * NODE_DIM + d] = sum / (float)c;
    }
}

// ---------------------------------------------------------------------------
extern "C" void kernel_launch(void* const* d_in, const int* in_sizes, int n_in,
                              void* d_out, int out_size, void* d_ws, size_t ws_size,
                              hipStream_t stream) {
    const float* x         = (const float*)d_in[0];
    const float* edge_attr = (const float*)d_in[1];
    const int*   ei        = (const int*)d_in[2];
    const int*   batch     = (const int*)d_in[3];
    const float* Wd        = (const float*)d_in[4];
    const float* fW1       = (const float*)d_in[5];
    const float* fb1       = (const float*)d_in[6];
    const float* fW2       = (const float*)d_in[7];
    const float* fb2       = (const float*)d_in[8];
    const float* av        = (const float*)d_in[9];
    const float* oW1       = (const float*)d_in[10];
    const float* ob1       = (const float*)d_in[11];
    const float* oW2       = (const float*)d_in[12];
    const float* ob2       = (const float*)d_in[13];
    const float* nW1       = (const float*)d_in[14];
    const float* nb1       = (const float*)d_in[15];
    const float* nW2       = (const float*)d_in[16];
    const float* nb2       = (const float*)d_in[17];
    float* out = (float*)d_out;

    const int N = in_sizes[0] / NODE_DIM;   // 50000
    const int E = in_sizes[2] / 2;          // 800000
    const int G = NGRAPH;

    char* base = (char*)d_ws;
    size_t pos = 0;
    auto alloc = [&](size_t bytes) -> void* {
        pos = (pos + 255) & ~(size_t)255;
        void* r = base + pos;
        pos += bytes;
        return r;
    };
    int* cnt  = (int*)alloc((size_t)N * 4);
    int* cur  = (int*)alloc((size_t)N * 4);
    int* gcnt = (int*)alloc((size_t)G * 4);
    size_t zero_bytes = pos;
    int* off  = (int*)alloc((size_t)(N + 1) * 4);
    int* goff = (int*)alloc((size_t)(G + 1) * 4);
    int* eidx = (int*)alloc((size_t)E * 4);
    int* srcp = (int*)alloc((size_t)E * 4);
    float* score = (float*)alloc((size_t)E * 4);
    float* hd    = (float*)alloc((size_t)N * NODE_DIM * 4);
    float* h     = (float*)alloc((size_t)N * NODE_DIM * 4);
    float* agg   = (float*)alloc((size_t)N * NODE_DIM * 4);
    float* pooled = (float*)alloc((size_t)G * NODE_DIM * 4);
    float* t2     = (float*)alloc((size_t)G * HIDDEN * 4);
    unsigned short* ea_p  = (unsigned short*)alloc((size_t)E * EDGE_DIM * 2);
    unsigned short* ew    = (unsigned short*)alloc((size_t)E * NODE_DIM * 2);
    unsigned short* W1sw  = (unsigned short*)alloc((size_t)N_LAYERS * 8 * 64 * 8 * 2);
    unsigned short* W2sw  = (unsigned short*)alloc((size_t)N_LAYERS * 16 * 64 * 8 * 2);
    unsigned short* oW1sw = (unsigned short*)alloc((size_t)N_LAYERS * 16 * 64 * 8 * 2);
    unsigned short* oW2sw = (unsigned short*)alloc((size_t)N_LAYERS * 16 * 64 * 8 * 2);
    (void)ws_size;

    const int* src = ei;
    const int* tgt = ei + E;

    hipMemsetAsync(d_ws, 0, zero_bytes, stream);
    hist_kernel<<<(E + 255) / 256, 256, 0, stream>>>(tgt, cnt, E);
    scan_kernel<<<1, 1024, 0, stream>>>(cnt, off, N);
    scatter_kernel<<<(E + 255) / 256, 256, 0, stream>>>(src, tgt, off, cur, eidx, srcp, E);
    hist_kernel<<<(N + 255) / 256, 256, 0, stream>>>(batch, gcnt, N);
    gscan_kernel<<<1, 128, 0, stream>>>(gcnt, goff, G);
    perm_ea_kernel<<<(E + 255) / 256, 256, 0, stream>>>(edge_attr, eidx, ea_p, E);
    swizzle_w_kernel<<<N_LAYERS, 64, 0, stream>>>(fW1, fW2, oW1, oW2, W1sw, W2sw, oW1sw, oW2sw);
    hipMemcpyAsync(h, x, (size_t)N * NODE_DIM * 4, hipMemcpyDeviceToDevice, stream);

    const int node_tiles = (N + 15) / 16;
    for (int i = 0; i < N_LAYERS; ++i) {
        dense_kernel<NODE_DIM, NODE_DIM, false, false>
            <<<(N * NODE_DIM + 255) / 256, 256, 0, stream>>>(
                h, Wd + (size_t)i * NODE_DIM * NODE_DIM, nullptr, hd, N);
        edge_mfma_kernel<<<(E + 63) / 64, 256, 0, stream>>>(
            ea_p, hd,
            W1sw + (size_t)i * 8 * 64 * 8, fb1 + (size_t)i * HIDDEN,
            W2sw + (size_t)i * 16 * 64 * 8, fb2 + (size_t)i * NODE_DIM,
            av + (size_t)i * NODE_DIM, srcp, ew, score, E);
        agg_kernel<<<(N + 3) / 4, 256, 0, stream>>>(ew, score, hd, srcp, off, agg, N);
        node_mlp_kernel<<<(node_tiles + 3) / 4, 256, 0, stream>>>(
            agg,
            oW1sw + (size_t)i * 16 * 64 * 8, ob1 + (size_t)i * HIDDEN,
            oW2sw + (size_t)i * 16 * 64 * 8, ob2 + (size_t)i * NODE_DIM,
            h, N);
    }

    pool_kernel<<<G, 256, 0, stream>>>(h, goff, pooled);
    dense_kernel<NODE_DIM, HIDDEN, true, false>
        <<<(G * HIDDEN + 255) / 256, 256, 0, stream>>>(pooled, nW1, nb1, t2, G);
    dense_kernel<HIDDEN, OUT_DIM, false, false>
        <<<(G * OUT_DIM + 255) / 256, 256, 0, stream>>>(t2, nW2, nb2, out, G);
}

// Round 6
// 966.268 us; speedup vs baseline: 5.2598x; 1.2123x over previous
//
#include <hip/hip_runtime.h>
#include <hip/hip_bf16.h>
#include <math.h>

#define NODE_DIM 64
#define EDGE_DIM 32
#define HIDDEN   128
#define OUT_DIM  32
#define N_LAYERS 3
#define NGRAPH   128

typedef __attribute__((ext_vector_type(8))) short bf16x8;
typedef __attribute__((ext_vector_type(4))) float f32x4;

__device__ __forceinline__ unsigned short f2bf(float f) {
    unsigned u = __float_as_uint(f);
    u = (u + 0x7fffu + ((u >> 16) & 1u)) >> 16;
    return (unsigned short)u;
}
__device__ __forceinline__ float bf2f(unsigned short h) {
    return __uint_as_float((unsigned)h << 16);
}
// tanh(x) = sign(x) * (1 - e) / (1 + e), e = exp(-2|x|)
__device__ __forceinline__ float fast_tanh(float x) {
    float ax = fabsf(x);
    float e = __expf(-2.f * ax);
    float r = __builtin_amdgcn_rcpf(1.f + e);
    float t = (1.f - e) * r;
    return __builtin_copysignf(t, x);
}

// ---------------------------------------------------------------------------
// Two-level counting sort of edges by target node — LDS atomics only.
// Coarse bucket = tgt >> 7 (128 nodes per bucket). EPB = 4096 edges/block.
// ---------------------------------------------------------------------------
__global__ __launch_bounds__(256) void coarse_hist_kernel(
    const int* __restrict__ tgt, int* __restrict__ Hc, int E, int C, int NB) {
    __shared__ int lh[512];
    int blk = blockIdx.x, tid = threadIdx.x;
    for (int b = tid; b < C; b += 256) lh[b] = 0;
    __syncthreads();
    int base = blk * 4096;
#pragma unroll
    for (int i = 0; i < 16; ++i) {
        int e = base + i * 256 + tid;
        if (e < E) atomicAdd(&lh[tgt[e] >> 7], 1);
    }
    __syncthreads();
    for (int b = tid; b < C; b += 256) Hc[(size_t)b * NB + blk] = lh[b];
}

// generic single-block exclusive scan (1024 threads)
__global__ void scan_kernel(const int* __restrict__ c, int* __restrict__ o, int n) {
    __shared__ int sh[1024];
    int t = threadIdx.x;
    int chunk = (n + 1023) >> 10;
    int lo = t * chunk, hi = lo + chunk;
    if (hi > n) hi = n;
    if (lo > n) lo = n;
    int s = 0;
    for (int i = lo; i < hi; ++i) s += c[i];
    sh[t] = s;
    __syncthreads();
    for (int d = 1; d < 1024; d <<= 1) {
        int v = (t >= d) ? sh[t - d] : 0;
        __syncthreads();
        sh[t] += v;
        __syncthreads();
    }
    int run = sh[t] - s;
    for (int i = lo; i < hi; ++i) { o[i] = run; run += c[i]; }
    if (hi == n) o[n] = run;
}

__global__ __launch_bounds__(256) void coarse_scatter_kernel(
    const int* __restrict__ tgt, const int* __restrict__ Sc,
    int* __restrict__ tgtc, int* __restrict__ ec, int E, int C, int NB) {
    __shared__ int lb[512];
    int blk = blockIdx.x, tid = threadIdx.x;
    for (int b = tid; b < C; b += 256) lb[b] = Sc[(size_t)b * NB + blk];
    __syncthreads();
    int base = blk * 4096;
#pragma unroll
    for (int i = 0; i < 16; ++i) {
        int e = base + i * 256 + tid;
        if (e < E) {
            int t = tgt[e];
            int pos = atomicAdd(&lb[t >> 7], 1);
            tgtc[pos] = t;
            ec[pos] = e;
        }
    }
}

// One block per coarse bucket: fine 128-bin sort + off[] emission.
__global__ __launch_bounds__(256) void fine_sort_kernel(
    const int* __restrict__ Sc, const int* __restrict__ tgtc,
    const int* __restrict__ ec, const int* __restrict__ src,
    int* __restrict__ off, int* __restrict__ eidx, int* __restrict__ srcp,
    int E, int N, int C, int NB) {
    __shared__ int fh[128], fs[128], rb[128];
    int b = blockIdx.x, tid = threadIdx.x;
    int cb0 = Sc[(size_t)b * NB];
    int cb1 = (b + 1 < C) ? Sc[(size_t)(b + 1) * NB] : E;
    if (tid < 128) fh[tid] = 0;
    __syncthreads();
    for (int p = cb0 + tid; p < cb1; p += 256) atomicAdd(&fh[tgtc[p] & 127], 1);
    __syncthreads();
    if (tid < 128) fs[tid] = fh[tid];
    __syncthreads();
    for (int d = 1; d < 128; d <<= 1) {
        int v = 0;
        if (tid < 128 && tid >= d) v = fs[tid - d];
        __syncthreads();
        if (tid < 128) fs[tid] += v;
        __syncthreads();
    }
    if (tid < 128) {
        int ex = fs[tid] - fh[tid];  // exclusive base within bucket
        rb[tid] = ex;
        int node = (b << 7) + tid;
        if (node < N) off[node] = cb0 + ex;
    }
    if (b == C - 1 && tid == 0) off[N] = E;
    __syncthreads();
    for (int p = cb0 + tid; p < cb1; p += 256) {
        int t = tgtc[p];
        int r = atomicAdd(&rb[t & 127], 1);
        int fpos = cb0 + r;
        int e = ec[p];
        eidx[fpos] = e;
        srcp[fpos] = src[e];
    }
}

// batch is sorted: mark graph boundaries directly
__global__ void gbound_kernel(const int* __restrict__ batch, int* __restrict__ goff,
                              int N, int G) {
    int i = blockIdx.x * 256 + threadIdx.x;
    if (i >= N) return;
    int b = batch[i];
    if (i == 0) {
        for (int g = 0; g <= b; ++g) goff[g] = 0;
    } else {
        int bp = batch[i - 1];
        for (int g = bp + 1; g <= b; ++g) goff[g] = i;
    }
    if (i == N - 1) {
        for (int g = b + 1; g <= G; ++g) goff[g] = N;
    }
}

// ---------------------------------------------------------------------------
// Permute+convert edge_attr to bf16 in target-sorted order (coalesced writes)
// ---------------------------------------------------------------------------
__global__ __launch_bounds__(256) void perm_ea_kernel(
    const float* __restrict__ ea, const int* __restrict__ eidx,
    unsigned short* __restrict__ out, int E) {
    int p = blockIdx.x * 256 + threadIdx.x;
    if (p >= E) return;
    int e = eidx[p];
    const float4* r = (const float4*)(ea + (size_t)e * EDGE_DIM);
    union { unsigned short us[EDGE_DIM]; uint4 u4[EDGE_DIM / 8]; } tmp;
#pragma unroll
    for (int q = 0; q < EDGE_DIM / 4; ++q) {
        float4 v = r[q];
        tmp.us[4 * q]     = f2bf(v.x);
        tmp.us[4 * q + 1] = f2bf(v.y);
        tmp.us[4 * q + 2] = f2bf(v.z);
        tmp.us[4 * q + 3] = f2bf(v.w);
    }
    uint4* o = (uint4*)(out + (size_t)p * EDGE_DIM);
#pragma unroll
    for (int k = 0; k < EDGE_DIM / 8; ++k) o[k] = tmp.u4[k];
}

// ---------------------------------------------------------------------------
// Parallel weight swizzle into MFMA A-frag order: one block per 16x32 tile.
// 56 tiles/layer: [0,8) fW1, [8,24) fW2, [24,40) oW1, [40,56) oW2.
// out[((mt*nc + s)*64 + L)*8 + j] = bf16(W[(32s + 8q + j)*M + 16mt + e])
// ---------------------------------------------------------------------------
__global__ void swizzle_w_kernel(const float* __restrict__ fW1, const float* __restrict__ fW2,
                                 const float* __restrict__ oW1, const float* __restrict__ oW2,
                                 unsigned short* __restrict__ W1sw, unsigned short* __restrict__ W2sw,
                                 unsigned short* __restrict__ oW1sw, unsigned short* __restrict__ oW2sw) {
    int i = blockIdx.x / 56, r = blockIdx.x % 56;
    int L = threadIdx.x;
    int e = L & 15, q = L >> 4;
    const float* W;
    unsigned short* out;
    int K, M, t;
    if (r < 8)       { W = fW1 + (size_t)i * EDGE_DIM * HIDDEN;  out = W1sw  + (size_t)i * 8 * 512;  K = EDGE_DIM; M = HIDDEN;   t = r; }
    else if (r < 24) { W = fW2 + (size_t)i * HIDDEN * NODE_DIM;  out = W2sw  + (size_t)i * 16 * 512; K = HIDDEN;   M = NODE_DIM; t = r - 8; }
    else if (r < 40) { W = oW1 + (size_t)i * NODE_DIM * HIDDEN;  out = oW1sw + (size_t)i * 16 * 512; K = NODE_DIM; M = HIDDEN;   t = r - 24; }
    else             { W = oW2 + (size_t)i * HIDDEN * NODE_DIM;  out = oW2sw + (size_t)i * 16 * 512; K = HIDDEN;   M = NODE_DIM; t = r - 40; }
    int nc = K >> 5;
    int mt = t / nc, s = t - mt * nc;
    union { unsigned short us[8]; uint4 u4; } pk;
#pragma unroll
    for (int j = 0; j < 8; ++j)
        pk.us[j] = f2bf(W[(size_t)(32 * s + 8 * q + j) * M + 16 * mt + e]);
    *(uint4*)(out + ((size_t)t * 64 + L) * 8) = pk.u4;
}

#define HSTRIDE 136  // shorts; 128 + 8 pad, keeps 16B alignment for ds_read_b128

// ---------------------------------------------------------------------------
// MFMA edge kernel: wave per 16 edges (one-shot, high occupancy).
// ---------------------------------------------------------------------------
__global__ __launch_bounds__(256) void edge_mfma_kernel(
    const unsigned short* __restrict__ ea_p, const float* __restrict__ hd,
    const unsigned short* __restrict__ W1sw, const float* __restrict__ b1,
    const unsigned short* __restrict__ W2sw, const float* __restrict__ b2,
    const float* __restrict__ av, const int* __restrict__ srcp,
    unsigned short* __restrict__ ew, float* __restrict__ score, int E) {
    __shared__ unsigned short Hl[4][16 * HSTRIDE];
    int wave = threadIdx.x >> 6, lane = threadIdx.x & 63;
    int e = lane & 15, q = lane >> 4;
    int p0 = blockIdx.x * 64 + wave * 16;
    if (p0 >= E) return;

    bf16x8 eaf = *(const bf16x8*)(ea_p + (size_t)(p0 + e) * EDGE_DIM + q * 8);

    f32x4 c1[8];
#pragma unroll
    for (int t = 0; t < 8; ++t) {
        bf16x8 a = *(const bf16x8*)(W1sw + (t * 64 + lane) * 8);
        c1[t] = __builtin_amdgcn_mfma_f32_16x16x32_bf16(a, eaf, (f32x4){0.f, 0.f, 0.f, 0.f}, 0, 0, 0);
    }

    unsigned short* hrow = &Hl[wave][e * HSTRIDE];
#pragma unroll
    for (int t = 0; t < 8; ++t) {
        float4 b = *(const float4*)(b1 + 16 * t + 4 * q);
        unsigned h0 = f2bf(fast_tanh(c1[t][0] + b.x));
        unsigned h1 = f2bf(fast_tanh(c1[t][1] + b.y));
        unsigned h2 = f2bf(fast_tanh(c1[t][2] + b.z));
        unsigned h3 = f2bf(fast_tanh(c1[t][3] + b.w));
        uint2 pk;
        pk.x = h0 | (h1 << 16);
        pk.y = h2 | (h3 << 16);
        *(uint2*)(hrow + 16 * t + 4 * q) = pk;  // ds_write_b64
    }

    f32x4 c2[4] = {{0.f, 0.f, 0.f, 0.f}, {0.f, 0.f, 0.f, 0.f},
                   {0.f, 0.f, 0.f, 0.f}, {0.f, 0.f, 0.f, 0.f}};
#pragma unroll
    for (int s = 0; s < 4; ++s) {
        bf16x8 hf = *(const bf16x8*)(hrow + 32 * s + 8 * q);
#pragma unroll
        for (int nt = 0; nt < 4; ++nt) {
            bf16x8 a = *(const bf16x8*)(W2sw + ((nt * 4 + s) * 64 + lane) * 8);
            c2[nt] = __builtin_amdgcn_mfma_f32_16x16x32_bf16(a, hf, c2[nt], 0, 0, 0);
        }
    }

    int sidx = srcp[p0 + e];
    float sc = 0.f;
#pragma unroll
    for (int nt = 0; nt < 4; ++nt) {
        float4 bb = *(const float4*)(b2 + 16 * nt + 4 * q);
        float4 vv = *(const float4*)(av + 16 * nt + 4 * q);
        float4 hh = *(const float4*)(hd + (size_t)sidx * NODE_DIM + 16 * nt + 4 * q);
        float e0 = c2[nt][0] + bb.x, e1 = c2[nt][1] + bb.y;
        float e2 = c2[nt][2] + bb.z, e3 = c2[nt][3] + bb.w;
        uint2 pk;
        pk.x = (unsigned)f2bf(e0) | ((unsigned)f2bf(e1) << 16);
        pk.y = (unsigned)f2bf(e2) | ((unsigned)f2bf(e3) << 16);
        *(uint2*)(ew + (size_t)(p0 + e) * NODE_DIM + 16 * nt + 4 * q) = pk;
        sc += hh.x * e0 * vv.x + hh.y * e1 * vv.y + hh.z * e2 * vv.z + hh.w * e3 * vv.w;
    }
    sc += __shfl_xor(sc, 16, 64);
    sc += __shfl_xor(sc, 32, 64);
    if (q == 0) score[p0 + e] = sc;
}

// ---------------------------------------------------------------------------
// Fused node out-MLP (MFMA): delta = tanh(agg@oW1+b1)@oW2+b2; h += delta
// ---------------------------------------------------------------------------
__global__ __launch_bounds__(256) void node_mlp_kernel(
    const float* __restrict__ agg,
    const unsigned short* __restrict__ W1sw, const float* __restrict__ b1,
    const unsigned short* __restrict__ W2sw, const float* __restrict__ b2,
    float* __restrict__ h, int N) {
    __shared__ unsigned short Hl[4][16 * HSTRIDE];
    int wave = threadIdx.x >> 6, lane = threadIdx.x & 63;
    int e = lane & 15, q = lane >> 4;
    int n0 = (blockIdx.x * 4 + wave) * 16;
    if (n0 >= N) return;
    int ne = n0 + e;
    int neC = ne < N ? ne : N - 1;
    bool ok = ne < N;

    bf16x8 bfr[2];
#pragma unroll
    for (int s = 0; s < 2; ++s) {
        const float4* ar = (const float4*)(agg + (size_t)neC * NODE_DIM + 32 * s + 8 * q);
        float4 x0 = ar[0], x1 = ar[1];
        union { bf16x8 v; unsigned short us[8]; } u;
        u.us[0] = f2bf(x0.x); u.us[1] = f2bf(x0.y);
        u.us[2] = f2bf(x0.z); u.us[3] = f2bf(x0.w);
        u.us[4] = f2bf(x1.x); u.us[5] = f2bf(x1.y);
        u.us[6] = f2bf(x1.z); u.us[7] = f2bf(x1.w);
        bfr[s] = u.v;
    }

    f32x4 c1[8];
#pragma unroll
    for (int t = 0; t < 8; ++t) {
        bf16x8 a0 = *(const bf16x8*)(W1sw + ((t * 2 + 0) * 64 + lane) * 8);
        bf16x8 a1 = *(const bf16x8*)(W1sw + ((t * 2 + 1) * 64 + lane) * 8);
        c1[t] = __builtin_amdgcn_mfma_f32_16x16x32_bf16(a0, bfr[0], (f32x4){0.f, 0.f, 0.f, 0.f}, 0, 0, 0);
        c1[t] = __builtin_amdgcn_mfma_f32_16x16x32_bf16(a1, bfr[1], c1[t], 0, 0, 0);
    }

    unsigned short* hrow = &Hl[wave][e * HSTRIDE];
#pragma unroll
    for (int t = 0; t < 8; ++t) {
        float4 b = *(const float4*)(b1 + 16 * t + 4 * q);
        unsigned h0 = f2bf(fast_tanh(c1[t][0] + b.x));
        unsigned h1 = f2bf(fast_tanh(c1[t][1] + b.y));
        unsigned h2 = f2bf(fast_tanh(c1[t][2] + b.z));
        unsigned h3 = f2bf(fast_tanh(c1[t][3] + b.w));
        uint2 pk;
        pk.x = h0 | (h1 << 16);
        pk.y = h2 | (h3 << 16);
        *(uint2*)(hrow + 16 * t + 4 * q) = pk;
    }

    f32x4 c2[4] = {{0.f, 0.f, 0.f, 0.f}, {0.f, 0.f, 0.f, 0.f},
                   {0.f, 0.f, 0.f, 0.f}, {0.f, 0.f, 0.f, 0.f}};
#pragma unroll
    for (int s = 0; s < 4; ++s) {
        bf16x8 hf = *(const bf16x8*)(hrow + 32 * s + 8 * q);
#pragma unroll
        for (int nt = 0; nt < 4; ++nt) {
            bf16x8 a = *(const bf16x8*)(W2sw + ((nt * 4 + s) * 64 + lane) * 8);
            c2[nt] = __builtin_amdgcn_mfma_f32_16x16x32_bf16(a, hf, c2[nt], 0, 0, 0);
        }
    }

    if (ok) {
#pragma unroll
        for (int nt = 0; nt < 4; ++nt) {
            float4 bb = *(const float4*)(b2 + 16 * nt + 4 * q);
            float4* hp = (float4*)(h + (size_t)ne * NODE_DIM + 16 * nt + 4 * q);
            float4 hv = *hp;
            hv.x += c2[nt][0] + bb.x;
            hv.y += c2[nt][1] + bb.y;
            hv.z += c2[nt][2] + bb.z;
            hv.w += c2[nt][3] + bb.w;
            *hp = hv;
        }
    }
}

// ---------------------------------------------------------------------------
// Generic dense layer (fp32): hd and final output MLP
// ---------------------------------------------------------------------------
template <int K, int M, bool ACT, bool RESID>
__global__ __launch_bounds__(256) void dense_kernel(
    const float* __restrict__ X, const float* __restrict__ W,
    const float* __restrict__ bias, float* __restrict__ Y, int rows) {
    int tid = blockIdx.x * 256 + threadIdx.x;
    int row = tid / M;
    int d = tid - row * M;
    if (row >= rows) return;
    if (M >= 64) row = __builtin_amdgcn_readfirstlane(row);
    const float* __restrict__ x = X + (size_t)row * K;
    float acc = bias ? bias[d] : 0.f;
#pragma unroll
    for (int k = 0; k < K; ++k) acc += x[k] * W[k * M + d];
    if (ACT) acc = fast_tanh(acc);
    if (RESID) acc += Y[(size_t)row * M + d];
    Y[(size_t)row * M + d] = acc;
}

// ---------------------------------------------------------------------------
// Aggregation: wave per node; 8 edges x 8 dim-groups per iteration
// ---------------------------------------------------------------------------
__global__ __launch_bounds__(256) void agg_kernel(
    const unsigned short* __restrict__ ew, const float* __restrict__ score,
    const float* __restrict__ hd, const int* __restrict__ srcp,
    const int* __restrict__ off, float* __restrict__ agg, int n) {
    int tid = blockIdx.x * 256 + threadIdx.x;
    int wid = tid >> 6;
    int lane = threadIdx.x & 63;
    if (wid >= n) return;
    wid = __builtin_amdgcn_readfirstlane(wid);
    int o0 = off[wid], o1 = off[wid + 1];
    int g = lane >> 3, s = lane & 7;
    if (o1 <= o0) {
        if (g == 0) {
            float4 z = {0.f, 0.f, 0.f, 0.f};
            float4* dst = (float4*)(agg + (size_t)wid * NODE_DIM + s * 8);
            dst[0] = z; dst[1] = z;
        }
        return;
    }
    float m = -INFINITY;
    for (int p = o0 + lane; p < o1; p += 64) m = fmaxf(m, score[p]);
#pragma unroll
    for (int t = 32; t; t >>= 1) m = fmaxf(m, __shfl_xor(m, t, 64));
    float dsum = 0.f;
    for (int p = o0 + lane; p < o1; p += 64) dsum += __expf(score[p] - m);
#pragma unroll
    for (int t = 32; t; t >>= 1) dsum += __shfl_xor(dsum, t, 64);

    float acc[8] = {0.f, 0.f, 0.f, 0.f, 0.f, 0.f, 0.f, 0.f};
    for (int p = o0; p < o1; p += 8) {
        int pe = p + g;
        int pc = (pe < o1) ? pe : (o1 - 1);
        float w = (pe < o1) ? __expf(score[pc] - m) : 0.f;
        int sidx = srcp[pc];
        union { bf16x8 v; unsigned short us[8]; } eu;
        eu.v = *(const bf16x8*)(ew + (size_t)pc * NODE_DIM + s * 8);
        const float4* hr = (const float4*)(hd + (size_t)sidx * NODE_DIM + s * 8);
        float4 h0 = hr[0], h1 = hr[1];
        acc[0] += w * h0.x * bf2f(eu.us[0]);
        acc[1] += w * h0.y * bf2f(eu.us[1]);
        acc[2] += w * h0.z * bf2f(eu.us[2]);
        acc[3] += w * h0.w * bf2f(eu.us[3]);
        acc[4] += w * h1.x * bf2f(eu.us[4]);
        acc[5] += w * h1.y * bf2f(eu.us[5]);
        acc[6] += w * h1.z * bf2f(eu.us[6]);
        acc[7] += w * h1.w * bf2f(eu.us[7]);
    }
#pragma unroll
    for (int j = 0; j < 8; ++j) {
        acc[j] += __shfl_xor(acc[j], 8, 64);
        acc[j] += __shfl_xor(acc[j], 16, 64);
        acc[j] += __shfl_xor(acc[j], 32, 64);
    }
    if (g == 0) {
        float inv = __builtin_amdgcn_rcpf(dsum);
        inv = inv * (2.f - dsum * inv);
        float4 r0 = {acc[0] * inv, acc[1] * inv, acc[2] * inv, acc[3] * inv};
        float4 r1 = {acc[4] * inv, acc[5] * inv, acc[6] * inv, acc[7] * inv};
        float4* dst = (float4*)(agg + (size_t)wid * NODE_DIM + s * 8);
        dst[0] = r0; dst[1] = r1;
    }
}

// ---------------------------------------------------------------------------
// Mean pool per graph: 4 waves per graph + LDS reduce
// ---------------------------------------------------------------------------
__global__ __launch_bounds__(256) void pool_kernel(const float* __restrict__ h,
                                                   const int* __restrict__ goff,
                                                   float* __restrict__ pooled) {
    __shared__ float sh[4][NODE_DIM];
    int g = blockIdx.x;
    int w = threadIdx.x >> 6, d = threadIdx.x & 63;
    int o0 = goff[g], o1 = goff[g + 1];
    float acc = 0.f;
    for (int n = o0 + w; n < o1; n += 4) acc += h[(size_t)n * NODE_DIM + d];
    sh[w][d] = acc;
    __syncthreads();
    if (w == 0) {
        float sum = sh[0][d] + sh[1][d] + sh[2][d] + sh[3][d];
        int c = o1 - o0;
        if (c < 1) c = 1;
        pooled[g * NODE_DIM + d] = sum / (float)c;
    }
}

// ---------------------------------------------------------------------------
extern "C" void kernel_launch(void* const* d_in, const int* in_sizes, int n_in,
                              void* d_out, int out_size, void* d_ws, size_t ws_size,
                              hipStream_t stream) {
    const float* x         = (const float*)d_in[0];
    const float* edge_attr = (const float*)d_in[1];
    const int*   ei        = (const int*)d_in[2];
    const int*   batch     = (const int*)d_in[3];
    const float* Wd        = (const float*)d_in[4];
    const float* fW1       = (const float*)d_in[5];
    const float* fb1       = (const float*)d_in[6];
    const float* fW2       = (const float*)d_in[7];
    const float* fb2       = (const float*)d_in[8];
    const float* av        = (const float*)d_in[9];
    const float* oW1       = (const float*)d_in[10];
    const float* ob1       = (const float*)d_in[11];
    const float* oW2       = (const float*)d_in[12];
    const float* ob2       = (const float*)d_in[13];
    const float* nW1       = (const float*)d_in[14];
    const float* nb1       = (const float*)d_in[15];
    const float* nW2       = (const float*)d_in[16];
    const float* nb2       = (const float*)d_in[17];
    float* out = (float*)d_out;

    const int N = in_sizes[0] / NODE_DIM;   // 50000
    const int E = in_sizes[2] / 2;          // 800000
    const int G = NGRAPH;
    const int NB = (E + 4095) / 4096;       // coarse blocks
    const int C  = (N + 127) >> 7;          // coarse buckets (<=512)

    char* base = (char*)d_ws;
    size_t pos = 0;
    auto alloc = [&](size_t bytes) -> void* {
        pos = (pos + 255) & ~(size_t)255;
        void* r = base + pos;
        pos += bytes;
        return r;
    };
    int* Hc   = (int*)alloc((size_t)C * NB * 4);
    int* Sc   = (int*)alloc(((size_t)C * NB + 1) * 4);
    int* tgtc = (int*)alloc((size_t)E * 4);
    int* ec   = (int*)alloc((size_t)E * 4);
    int* off  = (int*)alloc((size_t)(N + 1) * 4);
    int* goff = (int*)alloc((size_t)(G + 1) * 4);
    int* eidx = (int*)alloc((size_t)E * 4);
    int* srcp = (int*)alloc((size_t)E * 4);
    float* score = (float*)alloc((size_t)E * 4);
    float* hd    = (float*)alloc((size_t)N * NODE_DIM * 4);
    float* h     = (float*)alloc((size_t)N * NODE_DIM * 4);
    float* agg   = (float*)alloc((size_t)N * NODE_DIM * 4);
    float* pooled = (float*)alloc((size_t)G * NODE_DIM * 4);
    float* t2     = (float*)alloc((size_t)G * HIDDEN * 4);
    unsigned short* ea_p  = (unsigned short*)alloc((size_t)E * EDGE_DIM * 2);
    unsigned short* ew    = (unsigned short*)alloc((size_t)E * NODE_DIM * 2);
    unsigned short* W1sw  = (unsigned short*)alloc((size_t)N_LAYERS * 8 * 512 * 2);
    unsigned short* W2sw  = (unsigned short*)alloc((size_t)N_LAYERS * 16 * 512 * 2);
    unsigned short* oW1sw = (unsigned short*)alloc((size_t)N_LAYERS * 16 * 512 * 2);
    unsigned short* oW2sw = (unsigned short*)alloc((size_t)N_LAYERS * 16 * 512 * 2);
    (void)ws_size;

    const int* src = ei;
    const int* tgt = ei + E;

    // --- prep: two-level counting sort (no global atomics) ---
    coarse_hist_kernel<<<NB, 256, 0, stream>>>(tgt, Hc, E, C, NB);
    scan_kernel<<<1, 1024, 0, stream>>>(Hc, Sc, C * NB);
    coarse_scatter_kernel<<<NB, 256, 0, stream>>>(tgt, Sc, tgtc, ec, E, C, NB);
    fine_sort_kernel<<<C, 256, 0, stream>>>(Sc, tgtc, ec, src, off, eidx, srcp, E, N, C, NB);
    gbound_kernel<<<(N + 255) / 256, 256, 0, stream>>>(batch, goff, N, G);
    perm_ea_kernel<<<(E + 255) / 256, 256, 0, stream>>>(edge_attr, eidx, ea_p, E);
    swizzle_w_kernel<<<N_LAYERS * 56, 64, 0, stream>>>(fW1, fW2, oW1, oW2, W1sw, W2sw, oW1sw, oW2sw);
    hipMemcpyAsync(h, x, (size_t)N * NODE_DIM * 4, hipMemcpyDeviceToDevice, stream);

    const int node_tiles = (N + 15) / 16;
    for (int i = 0; i < N_LAYERS; ++i) {
        dense_kernel<NODE_DIM, NODE_DIM, false, false>
            <<<(N * NODE_DIM + 255) / 256, 256, 0, stream>>>(
                h, Wd + (size_t)i * NODE_DIM * NODE_DIM, nullptr, hd, N);
        edge_mfma_kernel<<<(E + 63) / 64, 256, 0, stream>>>(
            ea_p, hd,
            W1sw + (size_t)i * 8 * 512, fb1 + (size_t)i * HIDDEN,
            W2sw + (size_t)i * 16 * 512, fb2 + (size_t)i * NODE_DIM,
            av + (size_t)i * NODE_DIM, srcp, ew, score, E);
        agg_kernel<<<(N + 3) / 4, 256, 0, stream>>>(ew, score, hd, srcp, off, agg, N);
        node_mlp_kernel<<<(node_tiles + 3) / 4, 256, 0, stream>>>(
            agg,
            oW1sw + (size_t)i * 16 * 512, ob1 + (size_t)i * HIDDEN,
            oW2sw + (size_t)i * 16 * 512, ob2 + (size_t)i * NODE_DIM,
            h, N);
    }

    pool_kernel<<<G, 256, 0, stream>>>(h, goff, pooled);
    dense_kernel<NODE_DIM, HIDDEN, true, false>
        <<<(G * HIDDEN + 255) / 256, 256, 0, stream>>>(pooled, nW1, nb1, t2, G);
    dense_kernel<HIDDEN, OUT_DIM, false, false>
        <<<(G * OUT_DIM + 255) / 256, 256, 0, stream>>>(t2, nW2, nb2, out, G);
}

// Round 7
// 853.266 us; speedup vs baseline: 5.9564x; 1.1324x over previous
//
#include <hip/hip_runtime.h>
#include <hip/hip_bf16.h>
#include <math.h>

#define NODE_DIM 64
#define EDGE_DIM 32
#define HIDDEN   128
#define OUT_DIM  32
#define N_LAYERS 3
#define NGRAPH   128

typedef __attribute__((ext_vector_type(8))) short bf16x8;
typedef __attribute__((ext_vector_type(4))) float f32x4;

__device__ __forceinline__ unsigned short f2bf(float f) {
    unsigned u = __float_as_uint(f);
    u = (u + 0x7fffu + ((u >> 16) & 1u)) >> 16;
    return (unsigned short)u;
}
__device__ __forceinline__ float bf2f(unsigned short h) {
    return __uint_as_float((unsigned)h << 16);
}
// tanh(x) = sign(x) * (1 - e) / (1 + e), e = exp(-2|x|)
__device__ __forceinline__ float fast_tanh(float x) {
    float ax = fabsf(x);
    float e = __expf(-2.f * ax);
    float r = __builtin_amdgcn_rcpf(1.f + e);
    float t = (1.f - e) * r;
    return __builtin_copysignf(t, x);
}

// ---------------------------------------------------------------------------
// Two-level counting sort of edges by target node — LDS atomics only.
// Coarse bucket = tgt >> 7 (128 nodes per bucket). EPB = 4096 edges/block.
// ---------------------------------------------------------------------------
__global__ __launch_bounds__(256) void coarse_hist_kernel(
    const int* __restrict__ tgt, int* __restrict__ Hc, int E, int C, int NB) {
    __shared__ int lh[512];
    int blk = blockIdx.x, tid = threadIdx.x;
    for (int b = tid; b < C; b += 256) lh[b] = 0;
    __syncthreads();
    int base = blk * 4096;
#pragma unroll
    for (int i = 0; i < 16; ++i) {
        int e = base + i * 256 + tid;
        if (e < E) atomicAdd(&lh[tgt[e] >> 7], 1);
    }
    __syncthreads();
    for (int b = tid; b < C; b += 256) Hc[(size_t)b * NB + blk] = lh[b];
}

// ---------------------------------------------------------------------------
// Hierarchical exclusive scan (3 phases), n up to 256*1024 elements
// ---------------------------------------------------------------------------
__global__ __launch_bounds__(256) void scan1_kernel(const int* __restrict__ c,
                                                    int* __restrict__ o,
                                                    int* __restrict__ bsum, int n) {
    __shared__ int sh[256];
    int b = blockIdx.x, t = threadIdx.x;
    int i = b * 256 + t;
    int v = (i < n) ? c[i] : 0;
    sh[t] = v;
    __syncthreads();
    for (int d = 1; d < 256; d <<= 1) {
        int u = (t >= d) ? sh[t - d] : 0;
        __syncthreads();
        sh[t] += u;
        __syncthreads();
    }
    if (i < n) o[i] = sh[t] - v;          // exclusive within block
    if (t == 255) bsum[b] = sh[255];      // block total
}

__global__ void scan2_kernel(int* __restrict__ bsum, int nb) {
    __shared__ int sh[1024];
    int t = threadIdx.x;
    int v = (t < nb) ? bsum[t] : 0;
    sh[t] = v;
    __syncthreads();
    for (int d = 1; d < 1024; d <<= 1) {
        int u = (t >= d) ? sh[t - d] : 0;
        __syncthreads();
        sh[t] += u;
        __syncthreads();
    }
    if (t < nb) bsum[t] = sh[t] - v;      // exclusive block offsets
}

__global__ __launch_bounds__(256) void scan3_kernel(int* __restrict__ o,
                                                    const int* __restrict__ bsum, int n) {
    int i = blockIdx.x * 256 + threadIdx.x;
    if (i < n) o[i] += bsum[blockIdx.x];
}

__global__ __launch_bounds__(256) void coarse_scatter_kernel(
    const int* __restrict__ tgt, const int* __restrict__ Sc,
    int* __restrict__ tgtc, int* __restrict__ ec, int E, int C, int NB) {
    __shared__ int lb[512];
    int blk = blockIdx.x, tid = threadIdx.x;
    for (int b = tid; b < C; b += 256) lb[b] = Sc[(size_t)b * NB + blk];
    __syncthreads();
    int base = blk * 4096;
#pragma unroll
    for (int i = 0; i < 16; ++i) {
        int e = base + i * 256 + tid;
        if (e < E) {
            int t = tgt[e];
            int pos = atomicAdd(&lb[t >> 7], 1);
            tgtc[pos] = t;
            ec[pos] = e;
        }
    }
}

// One block per coarse bucket: fine 128-bin sort + off[] emission.
__global__ __launch_bounds__(256) void fine_sort_kernel(
    const int* __restrict__ Sc, const int* __restrict__ tgtc,
    const int* __restrict__ ec, const int* __restrict__ src,
    int* __restrict__ off, int* __restrict__ eidx, int* __restrict__ srcp,
    int E, int N, int C, int NB) {
    __shared__ int fh[128], fs[128], rb[128];
    int b = blockIdx.x, tid = threadIdx.x;
    int cb0 = Sc[(size_t)b * NB];
    int cb1 = (b + 1 < C) ? Sc[(size_t)(b + 1) * NB] : E;
    if (tid < 128) fh[tid] = 0;
    __syncthreads();
    for (int p = cb0 + tid; p < cb1; p += 256) atomicAdd(&fh[tgtc[p] & 127], 1);
    __syncthreads();
    if (tid < 128) fs[tid] = fh[tid];
    __syncthreads();
    for (int d = 1; d < 128; d <<= 1) {
        int v = 0;
        if (tid < 128 && tid >= d) v = fs[tid - d];
        __syncthreads();
        if (tid < 128) fs[tid] += v;
        __syncthreads();
    }
    if (tid < 128) {
        int ex = fs[tid] - fh[tid];  // exclusive base within bucket
        rb[tid] = ex;
        int node = (b << 7) + tid;
        if (node < N) off[node] = cb0 + ex;
    }
    if (b == C - 1 && tid == 0) off[N] = E;
    __syncthreads();
    for (int p = cb0 + tid; p < cb1; p += 256) {
        int t = tgtc[p];
        int r = atomicAdd(&rb[t & 127], 1);
        int fpos = cb0 + r;
        int e = ec[p];
        eidx[fpos] = e;
        srcp[fpos] = src[e];
    }
}

// batch is sorted: mark graph boundaries directly
__global__ void gbound_kernel(const int* __restrict__ batch, int* __restrict__ goff,
                              int N, int G) {
    int i = blockIdx.x * 256 + threadIdx.x;
    if (i >= N) return;
    int b = batch[i];
    if (i == 0) {
        for (int g = 0; g <= b; ++g) goff[g] = 0;
    } else {
        int bp = batch[i - 1];
        for (int g = bp + 1; g <= b; ++g) goff[g] = i;
    }
    if (i == N - 1) {
        for (int g = b + 1; g <= G; ++g) goff[g] = N;
    }
}

// ---------------------------------------------------------------------------
// Permute+convert edge_attr to bf16 in target-sorted order (coalesced writes)
// ---------------------------------------------------------------------------
__global__ __launch_bounds__(256) void perm_ea_kernel(
    const float* __restrict__ ea, const int* __restrict__ eidx,
    unsigned short* __restrict__ out, int E) {
    int p = blockIdx.x * 256 + threadIdx.x;
    if (p >= E) return;
    int e = eidx[p];
    const float4* r = (const float4*)(ea + (size_t)e * EDGE_DIM);
    union { unsigned short us[EDGE_DIM]; uint4 u4[EDGE_DIM / 8]; } tmp;
#pragma unroll
    for (int q = 0; q < EDGE_DIM / 4; ++q) {
        float4 v = r[q];
        tmp.us[4 * q]     = f2bf(v.x);
        tmp.us[4 * q + 1] = f2bf(v.y);
        tmp.us[4 * q + 2] = f2bf(v.z);
        tmp.us[4 * q + 3] = f2bf(v.w);
    }
    uint4* o = (uint4*)(out + (size_t)p * EDGE_DIM);
#pragma unroll
    for (int k = 0; k < EDGE_DIM / 8; ++k) o[k] = tmp.u4[k];
}

// ---------------------------------------------------------------------------
// Parallel weight swizzle into MFMA A-frag order: one block per 16x32 tile.
// 56 tiles/layer: [0,8) fW1, [8,24) fW2, [24,40) oW1, [40,56) oW2.
// ---------------------------------------------------------------------------
__global__ void swizzle_w_kernel(const float* __restrict__ fW1, const float* __restrict__ fW2,
                                 const float* __restrict__ oW1, const float* __restrict__ oW2,
                                 unsigned short* __restrict__ W1sw, unsigned short* __restrict__ W2sw,
                                 unsigned short* __restrict__ oW1sw, unsigned short* __restrict__ oW2sw) {
    int i = blockIdx.x / 56, r = blockIdx.x % 56;
    int L = threadIdx.x;
    int e = L & 15, q = L >> 4;
    const float* W;
    unsigned short* out;
    int K, M, t;
    if (r < 8)       { W = fW1 + (size_t)i * EDGE_DIM * HIDDEN;  out = W1sw  + (size_t)i * 8 * 512;  K = EDGE_DIM; M = HIDDEN;   t = r; }
    else if (r < 24) { W = fW2 + (size_t)i * HIDDEN * NODE_DIM;  out = W2sw  + (size_t)i * 16 * 512; K = HIDDEN;   M = NODE_DIM; t = r - 8; }
    else if (r < 40) { W = oW1 + (size_t)i * NODE_DIM * HIDDEN;  out = oW1sw + (size_t)i * 16 * 512; K = NODE_DIM; M = HIDDEN;   t = r - 24; }
    else             { W = oW2 + (size_t)i * HIDDEN * NODE_DIM;  out = oW2sw + (size_t)i * 16 * 512; K = HIDDEN;   M = NODE_DIM; t = r - 40; }
    int nc = K >> 5;
    int mt = t / nc, s = t - mt * nc;
    union { unsigned short us[8]; uint4 u4; } pk;
#pragma unroll
    for (int j = 0; j < 8; ++j)
        pk.us[j] = f2bf(W[(size_t)(32 * s + 8 * q + j) * M + 16 * mt + e]);
    *(uint4*)(out + ((size_t)t * 64 + L) * 8) = pk.u4;
}

#define HSTRIDE 136  // shorts; 128 + 8 pad, keeps 16B alignment for ds_read_b128

// ---------------------------------------------------------------------------
// MFMA edge kernel: wave per 16 edges (one-shot, high occupancy).
// ---------------------------------------------------------------------------
__global__ __launch_bounds__(256) void edge_mfma_kernel(
    const unsigned short* __restrict__ ea_p, const float* __restrict__ hd,
    const unsigned short* __restrict__ W1sw, const float* __restrict__ b1,
    const unsigned short* __restrict__ W2sw, const float* __restrict__ b2,
    const float* __restrict__ av, const int* __restrict__ srcp,
    unsigned short* __restrict__ ew, float* __restrict__ score, int E) {
    __shared__ unsigned short Hl[4][16 * HSTRIDE];
    int wave = threadIdx.x >> 6, lane = threadIdx.x & 63;
    int e = lane & 15, q = lane >> 4;
    int p0 = blockIdx.x * 64 + wave * 16;
    if (p0 >= E) return;

    bf16x8 eaf = *(const bf16x8*)(ea_p + (size_t)(p0 + e) * EDGE_DIM + q * 8);

    f32x4 c1[8];
#pragma unroll
    for (int t = 0; t < 8; ++t) {
        bf16x8 a = *(const bf16x8*)(W1sw + (t * 64 + lane) * 8);
        c1[t] = __builtin_amdgcn_mfma_f32_16x16x32_bf16(a, eaf, (f32x4){0.f, 0.f, 0.f, 0.f}, 0, 0, 0);
    }

    unsigned short* hrow = &Hl[wave][e * HSTRIDE];
#pragma unroll
    for (int t = 0; t < 8; ++t) {
        float4 b = *(const float4*)(b1 + 16 * t + 4 * q);
        unsigned h0 = f2bf(fast_tanh(c1[t][0] + b.x));
        unsigned h1 = f2bf(fast_tanh(c1[t][1] + b.y));
        unsigned h2 = f2bf(fast_tanh(c1[t][2] + b.z));
        unsigned h3 = f2bf(fast_tanh(c1[t][3] + b.w));
        uint2 pk;
        pk.x = h0 | (h1 << 16);
        pk.y = h2 | (h3 << 16);
        *(uint2*)(hrow + 16 * t + 4 * q) = pk;  // ds_write_b64
    }

    f32x4 c2[4] = {{0.f, 0.f, 0.f, 0.f}, {0.f, 0.f, 0.f, 0.f},
                   {0.f, 0.f, 0.f, 0.f}, {0.f, 0.f, 0.f, 0.f}};
#pragma unroll
    for (int s = 0; s < 4; ++s) {
        bf16x8 hf = *(const bf16x8*)(hrow + 32 * s + 8 * q);
#pragma unroll
        for (int nt = 0; nt < 4; ++nt) {
            bf16x8 a = *(const bf16x8*)(W2sw + ((nt * 4 + s) * 64 + lane) * 8);
            c2[nt] = __builtin_amdgcn_mfma_f32_16x16x32_bf16(a, hf, c2[nt], 0, 0, 0);
        }
    }

    int sidx = srcp[p0 + e];
    float sc = 0.f;
#pragma unroll
    for (int nt = 0; nt < 4; ++nt) {
        float4 bb = *(const float4*)(b2 + 16 * nt + 4 * q);
        float4 vv = *(const float4*)(av + 16 * nt + 4 * q);
        float4 hh = *(const float4*)(hd + (size_t)sidx * NODE_DIM + 16 * nt + 4 * q);
        float e0 = c2[nt][0] + bb.x, e1 = c2[nt][1] + bb.y;
        float e2 = c2[nt][2] + bb.z, e3 = c2[nt][3] + bb.w;
        uint2 pk;
        pk.x = (unsigned)f2bf(e0) | ((unsigned)f2bf(e1) << 16);
        pk.y = (unsigned)f2bf(e2) | ((unsigned)f2bf(e3) << 16);
        *(uint2*)(ew + (size_t)(p0 + e) * NODE_DIM + 16 * nt + 4 * q) = pk;
        sc += hh.x * e0 * vv.x + hh.y * e1 * vv.y + hh.z * e2 * vv.z + hh.w * e3 * vv.w;
    }
    sc += __shfl_xor(sc, 16, 64);
    sc += __shfl_xor(sc, 32, 64);
    if (q == 0) score[p0 + e] = sc;
}

// ---------------------------------------------------------------------------
// Fused node out-MLP (MFMA): delta = tanh(agg@oW1+b1)@oW2+b2; h += delta
// ---------------------------------------------------------------------------
__global__ __launch_bounds__(256) void node_mlp_kernel(
    const float* __restrict__ agg,
    const unsigned short* __restrict__ W1sw, const float* __restrict__ b1,
    const unsigned short* __restrict__ W2sw, const float* __restrict__ b2,
    float* __restrict__ h, int N) {
    __shared__ unsigned short Hl[4][16 * HSTRIDE];
    int wave = threadIdx.x >> 6, lane = threadIdx.x & 63;
    int e = lane & 15, q = lane >> 4;
    int n0 = (blockIdx.x * 4 + wave) * 16;
    if (n0 >= N) return;
    int ne = n0 + e;
    int neC = ne < N ? ne : N - 1;
    bool ok = ne < N;

    bf16x8 bfr[2];
#pragma unroll
    for (int s = 0; s < 2; ++s) {
        const float4* ar = (const float4*)(agg + (size_t)neC * NODE_DIM + 32 * s + 8 * q);
        float4 x0 = ar[0], x1 = ar[1];
        union { bf16x8 v; unsigned short us[8]; } u;
        u.us[0] = f2bf(x0.x); u.us[1] = f2bf(x0.y);
        u.us[2] = f2bf(x0.z); u.us[3] = f2bf(x0.w);
        u.us[4] = f2bf(x1.x); u.us[5] = f2bf(x1.y);
        u.us[6] = f2bf(x1.z); u.us[7] = f2bf(x1.w);
        bfr[s] = u.v;
    }

    f32x4 c1[8];
#pragma unroll
    for (int t = 0; t < 8; ++t) {
        bf16x8 a0 = *(const bf16x8*)(W1sw + ((t * 2 + 0) * 64 + lane) * 8);
        bf16x8 a1 = *(const bf16x8*)(W1sw + ((t * 2 + 1) * 64 + lane) * 8);
        c1[t] = __builtin_amdgcn_mfma_f32_16x16x32_bf16(a0, bfr[0], (f32x4){0.f, 0.f, 0.f, 0.f}, 0, 0, 0);
        c1[t] = __builtin_amdgcn_mfma_f32_16x16x32_bf16(a1, bfr[1], c1[t], 0, 0, 0);
    }

    unsigned short* hrow = &Hl[wave][e * HSTRIDE];
#pragma unroll
    for (int t = 0; t < 8; ++t) {
        float4 b = *(const float4*)(b1 + 16 * t + 4 * q);
        unsigned h0 = f2bf(fast_tanh(c1[t][0] + b.x));
        unsigned h1 = f2bf(fast_tanh(c1[t][1] + b.y));
        unsigned h2 = f2bf(fast_tanh(c1[t][2] + b.z));
        unsigned h3 = f2bf(fast_tanh(c1[t][3] + b.w));
        uint2 pk;
        pk.x = h0 | (h1 << 16);
        pk.y = h2 | (h3 << 16);
        *(uint2*)(hrow + 16 * t + 4 * q) = pk;
    }

    f32x4 c2[4] = {{0.f, 0.f, 0.f, 0.f}, {0.f, 0.f, 0.f, 0.f},
                   {0.f, 0.f, 0.f, 0.f}, {0.f, 0.f, 0.f, 0.f}};
#pragma unroll
    for (int s = 0; s < 4; ++s) {
        bf16x8 hf = *(const bf16x8*)(hrow + 32 * s + 8 * q);
#pragma unroll
        for (int nt = 0; nt < 4; ++nt) {
            bf16x8 a = *(const bf16x8*)(W2sw + ((nt * 4 + s) * 64 + lane) * 8);
            c2[nt] = __builtin_amdgcn_mfma_f32_16x16x32_bf16(a, hf, c2[nt], 0, 0, 0);
        }
    }

    if (ok) {
#pragma unroll
        for (int nt = 0; nt < 4; ++nt) {
            float4 bb = *(const float4*)(b2 + 16 * nt + 4 * q);
            float4* hp = (float4*)(h + (size_t)ne * NODE_DIM + 16 * nt + 4 * q);
            float4 hv = *hp;
            hv.x += c2[nt][0] + bb.x;
            hv.y += c2[nt][1] + bb.y;
            hv.z += c2[nt][2] + bb.z;
            hv.w += c2[nt][3] + bb.w;
            *hp = hv;
        }
    }
}

// ---------------------------------------------------------------------------
// Generic dense layer (fp32): hd and final output MLP
// ---------------------------------------------------------------------------
template <int K, int M, bool ACT, bool RESID>
__global__ __launch_bounds__(256) void dense_kernel(
    const float* __restrict__ X, const float* __restrict__ W,
    const float* __restrict__ bias, float* __restrict__ Y, int rows) {
    int tid = blockIdx.x * 256 + threadIdx.x;
    int row = tid / M;
    int d = tid - row * M;
    if (row >= rows) return;
    if (M >= 64) row = __builtin_amdgcn_readfirstlane(row);
    const float* __restrict__ x = X + (size_t)row * K;
    float acc = bias ? bias[d] : 0.f;
#pragma unroll
    for (int k = 0; k < K; ++k) acc += x[k] * W[k * M + d];
    if (ACT) acc = fast_tanh(acc);
    if (RESID) acc += Y[(size_t)row * M + d];
    Y[(size_t)row * M + d] = acc;
}

// ---------------------------------------------------------------------------
// Aggregation: wave per node; 8 edges x 8 dim-groups per iteration
// ---------------------------------------------------------------------------
__global__ __launch_bounds__(256) void agg_kernel(
    const unsigned short* __restrict__ ew, const float* __restrict__ score,
    const float* __restrict__ hd, const int* __restrict__ srcp,
    const int* __restrict__ off, float* __restrict__ agg, int n) {
    int tid = blockIdx.x * 256 + threadIdx.x;
    int wid = tid >> 6;
    int lane = threadIdx.x & 63;
    if (wid >= n) return;
    wid = __builtin_amdgcn_readfirstlane(wid);
    int o0 = off[wid], o1 = off[wid + 1];
    int g = lane >> 3, s = lane & 7;
    if (o1 <= o0) {
        if (g == 0) {
            float4 z = {0.f, 0.f, 0.f, 0.f};
            float4* dst = (float4*)(agg + (size_t)wid * NODE_DIM + s * 8);
            dst[0] = z; dst[1] = z;
        }
        return;
    }
    float m = -INFINITY;
    for (int p = o0 + lane; p < o1; p += 64) m = fmaxf(m, score[p]);
#pragma unroll
    for (int t = 32; t; t >>= 1) m = fmaxf(m, __shfl_xor(m, t, 64));
    float dsum = 0.f;
    for (int p = o0 + lane; p < o1; p += 64) dsum += __expf(score[p] - m);
#pragma unroll
    for (int t = 32; t; t >>= 1) dsum += __shfl_xor(dsum, t, 64);

    float acc[8] = {0.f, 0.f, 0.f, 0.f, 0.f, 0.f, 0.f, 0.f};
    for (int p = o0; p < o1; p += 8) {
        int pe = p + g;
        int pc = (pe < o1) ? pe : (o1 - 1);
        float w = (pe < o1) ? __expf(score[pc] - m) : 0.f;
        int sidx = srcp[pc];
        union { bf16x8 v; unsigned short us[8]; } eu;
        eu.v = *(const bf16x8*)(ew + (size_t)pc * NODE_DIM + s * 8);
        const float4* hr = (const float4*)(hd + (size_t)sidx * NODE_DIM + s * 8);
        float4 h0 = hr[0], h1 = hr[1];
        acc[0] += w * h0.x * bf2f(eu.us[0]);
        acc[1] += w * h0.y * bf2f(eu.us[1]);
        acc[2] += w * h0.z * bf2f(eu.us[2]);
        acc[3] += w * h0.w * bf2f(eu.us[3]);
        acc[4] += w * h1.x * bf2f(eu.us[4]);
        acc[5] += w * h1.y * bf2f(eu.us[5]);
        acc[6] += w * h1.z * bf2f(eu.us[6]);
        acc[7] += w * h1.w * bf2f(eu.us[7]);
    }
#pragma unroll
    for (int j = 0; j < 8; ++j) {
        acc[j] += __shfl_xor(acc[j], 8, 64);
        acc[j] += __shfl_xor(acc[j], 16, 64);
        acc[j] += __shfl_xor(acc[j], 32, 64);
    }
    if (g == 0) {
        float inv = __builtin_amdgcn_rcpf(dsum);
        inv = inv * (2.f - dsum * inv);
        float4 r0 = {acc[0] * inv, acc[1] * inv, acc[2] * inv, acc[3] * inv};
        float4 r1 = {acc[4] * inv, acc[5] * inv, acc[6] * inv, acc[7] * inv};
        float4* dst = (float4*)(agg + (size_t)wid * NODE_DIM + s * 8);
        dst[0] = r0; dst[1] = r1;
    }
}

// ---------------------------------------------------------------------------
// Mean pool per graph: 4 waves per graph + LDS reduce
// ---------------------------------------------------------------------------
__global__ __launch_bounds__(256) void pool_kernel(const float* __restrict__ h,
                                                   const int* __restrict__ goff,
                                                   float* __restrict__ pooled) {
    __shared__ float sh[4][NODE_DIM];
    int g = blockIdx.x;
    int w = threadIdx.x >> 6, d = threadIdx.x & 63;
    int o0 = goff[g], o1 = goff[g + 1];
    float acc = 0.f;
    for (int n = o0 + w; n < o1; n += 4) acc += h[(size_t)n * NODE_DIM + d];
    sh[w][d] = acc;
    __syncthreads();
    if (w == 0) {
        float sum = sh[0][d] + sh[1][d] + sh[2][d] + sh[3][d];
        int c = o1 - o0;
        if (c < 1) c = 1;
        pooled[g * NODE_DIM + d] = sum / (float)c;
    }
}

// ---------------------------------------------------------------------------
extern "C" void kernel_launch(void* const* d_in, const int* in_sizes, int n_in,
                              void* d_out, int out_size, void* d_ws, size_t ws_size,
                              hipStream_t stream) {
    const float* x         = (const float*)d_in[0];
    const float* edge_attr = (const float*)d_in[1];
    const int*   ei        = (const int*)d_in[2];
    const int*   batch     = (const int*)d_in[3];
    const float* Wd        = (const float*)d_in[4];
    const float* fW1       = (const float*)d_in[5];
    const float* fb1       = (const float*)d_in[6];
    const float* fW2       = (const float*)d_in[7];
    const float* fb2       = (const float*)d_in[8];
    const float* av        = (const float*)d_in[9];
    const float* oW1       = (const float*)d_in[10];
    const float* ob1       = (const float*)d_in[11];
    const float* oW2       = (const float*)d_in[12];
    const float* ob2       = (const float*)d_in[13];
    const float* nW1       = (const float*)d_in[14];
    const float* nb1       = (const float*)d_in[15];
    const float* nW2       = (const float*)d_in[16];
    const float* nb2       = (const float*)d_in[17];
    float* out = (float*)d_out;

    const int N = in_sizes[0] / NODE_DIM;   // 50000
    const int E = in_sizes[2] / 2;          // 800000
    const int G = NGRAPH;
    const int NB = (E + 4095) / 4096;       // coarse blocks (196)
    const int C  = (N + 127) >> 7;          // coarse buckets (391)
    const int SN = C * NB;                  // scan length (76636)
    const int SB = (SN + 255) / 256;        // scan blocks (300, must be <=1024)

    char* base = (char*)d_ws;
    size_t pos = 0;
    auto alloc = [&](size_t bytes) -> void* {
        pos = (pos + 255) & ~(size_t)255;
        void* r = base + pos;
        pos += bytes;
        return r;
    };
    int* Hc   = (int*)alloc((size_t)SN * 4);
    int* Sc   = (int*)alloc(((size_t)SN + 1) * 4);
    int* bsum = (int*)alloc((size_t)1024 * 4);
    int* tgtc = (int*)alloc((size_t)E * 4);
    int* ec   = (int*)alloc((size_t)E * 4);
    int* off  = (int*)alloc((size_t)(N + 1) * 4);
    int* goff = (int*)alloc((size_t)(G + 1) * 4);
    int* eidx = (int*)alloc((size_t)E * 4);
    int* srcp = (int*)alloc((size_t)E * 4);
    float* score = (float*)alloc((size_t)E * 4);
    float* hd    = (float*)alloc((size_t)N * NODE_DIM * 4);
    float* h     = (float*)alloc((size_t)N * NODE_DIM * 4);
    float* agg   = (float*)alloc((size_t)N * NODE_DIM * 4);
    float* pooled = (float*)alloc((size_t)G * NODE_DIM * 4);
    float* t2     = (float*)alloc((size_t)G * HIDDEN * 4);
    unsigned short* ea_p  = (unsigned short*)alloc((size_t)E * EDGE_DIM * 2);
    unsigned short* ew    = (unsigned short*)alloc((size_t)E * NODE_DIM * 2);
    unsigned short* W1sw  = (unsigned short*)alloc((size_t)N_LAYERS * 8 * 512 * 2);
    unsigned short* W2sw  = (unsigned short*)alloc((size_t)N_LAYERS * 16 * 512 * 2);
    unsigned short* oW1sw = (unsigned short*)alloc((size_t)N_LAYERS * 16 * 512 * 2);
    unsigned short* oW2sw = (unsigned short*)alloc((size_t)N_LAYERS * 16 * 512 * 2);
    (void)ws_size;

    const int* src = ei;
    const int* tgt = ei + E;

    // --- prep: two-level counting sort, hierarchical scan (no global atomics) ---
    coarse_hist_kernel<<<NB, 256, 0, stream>>>(tgt, Hc, E, C, NB);
    scan1_kernel<<<SB, 256, 0, stream>>>(Hc, Sc, bsum, SN);
    scan2_kernel<<<1, 1024, 0, stream>>>(bsum, SB);
    scan3_kernel<<<SB, 256, 0, stream>>>(Sc, bsum, SN);
    coarse_scatter_kernel<<<NB, 256, 0, stream>>>(tgt, Sc, tgtc, ec, E, C, NB);
    fine_sort_kernel<<<C, 256, 0, stream>>>(Sc, tgtc, ec, src, off, eidx, srcp, E, N, C, NB);
    gbound_kernel<<<(N + 255) / 256, 256, 0, stream>>>(batch, goff, N, G);
    perm_ea_kernel<<<(E + 255) / 256, 256, 0, stream>>>(edge_attr, eidx, ea_p, E);
    swizzle_w_kernel<<<N_LAYERS * 56, 64, 0, stream>>>(fW1, fW2, oW1, oW2, W1sw, W2sw, oW1sw, oW2sw);
    hipMemcpyAsync(h, x, (size_t)N * NODE_DIM * 4, hipMemcpyDeviceToDevice, stream);

    const int node_tiles = (N + 15) / 16;
    for (int i = 0; i < N_LAYERS; ++i) {
        dense_kernel<NODE_DIM, NODE_DIM, false, false>
            <<<(N * NODE_DIM + 255) / 256, 256, 0, stream>>>(
                h, Wd + (size_t)i * NODE_DIM * NODE_DIM, nullptr, hd, N);
        edge_mfma_kernel<<<(E + 63) / 64, 256, 0, stream>>>(
            ea_p, hd,
            W1sw + (size_t)i * 8 * 512, fb1 + (size_t)i * HIDDEN,
            W2sw + (size_t)i * 16 * 512, fb2 + (size_t)i * NODE_DIM,
            av + (size_t)i * NODE_DIM, srcp, ew, score, E);
        agg_kernel<<<(N + 3) / 4, 256, 0, stream>>>(ew, score, hd, srcp, off, agg, N);
        node_mlp_kernel<<<(node_tiles + 3) / 4, 256, 0, stream>>>(
            agg,
            oW1sw + (size_t)i * 16 * 512, ob1 + (size_t)i * HIDDEN,
            oW2sw + (size_t)i * 16 * 512, ob2 + (size_t)i * NODE_DIM,
            h, N);
    }

    pool_kernel<<<G, 256, 0, stream>>>(h, goff, pooled);
    dense_kernel<NODE_DIM, HIDDEN, true, false>
        <<<(G * HIDDEN + 255) / 256, 256, 0, stream>>>(pooled, nW1, nb1, t2, G);
    dense_kernel<HIDDEN, OUT_DIM, false, false>
        <<<(G * OUT_DIM + 255) / 256, 256, 0, stream>>>(t2, nW2, nb2, out, G);
}